// Round 7
// baseline (303.744 us; speedup 1.0000x reference)
//
#include <hip/hip_runtime.h>
#include <hip/hip_fp16.h>
#include <math.h>

// GAT 2-layer forward, MI355X. FP32 in/out, int32 edge_index.
// R7: best-of-both — R5's proven gather patterns (full-wave-per-edge ushort
// in agg1, 4-subgroup scalar in agg2) + R6's proven gemm2/att2 fusion into
// agg1's epilogue (no out1 round-trip, one fewer kernel).

#define LRELU(v) ((v) > 0.f ? (v) : 0.2f * (v))
#define CAP 128          // agg LDS edge cache per node
#define BSH 8            // 256 nodes per bucket
#define BCAP 5120        // staged capacity per bucket
#define CHK 2048         // edges per k_scatter block

// Pass 1: bin edges by dst bucket, stage reordered in LDS, flush dense runs.
__global__ __launch_bounds__(256) void k_scatter(const int* __restrict__ ei, int* __restrict__ cursor,
                                                 int* __restrict__ stage, int E, int NBK) {
    __shared__ int sval[CHK];
    __shared__ int gaddr[CHK];
    __shared__ int sdst[CHK];
    __shared__ int hist[512];
    __shared__ int lbase[512];
    __shared__ int cnt2[512];
    __shared__ int gdelta[512];
    __shared__ int sA[512];
    int tid = threadIdx.x;
    int e0 = blockIdx.x * CHK;
    int nedge = E - e0; if (nedge > CHK) nedge = CHK;

    for (int i = tid; i < 512; i += 256) { hist[i] = 0; cnt2[i] = 0; }
    __syncthreads();
    for (int j = tid; j < nedge; j += 256) {
        int d = ei[E + e0 + j];
        sdst[j] = d;
        atomicAdd(&hist[d >> BSH], 1);
    }
    __syncthreads();
    sA[tid] = hist[tid]; sA[tid + 256] = hist[tid + 256];
    __syncthreads();
    for (int off = 1; off < 512; off <<= 1) {
        int r0 = sA[tid] + ((tid >= off) ? sA[tid - off] : 0);
        int r1 = sA[tid + 256] + ((tid + 256 >= off) ? sA[tid + 256 - off] : 0);
        __syncthreads();
        sA[tid] = r0; sA[tid + 256] = r1;
        __syncthreads();
    }
    for (int i = tid; i < 512; i += 256) lbase[i] = sA[i] - hist[i];
    __syncthreads();
    for (int b = tid; b < NBK; b += 256) {
        int c = hist[b];
        if (c > 0) {
            int rel = atomicAdd(&cursor[b], c);
            gdelta[b] = b * BCAP + rel - lbase[b];
        }
    }
    __syncthreads();
    for (int j = tid; j < nedge; j += 256) {
        int s = ei[e0 + j];
        int d = sdst[j];
        int b = d >> BSH;
        int r = atomicAdd(&cnt2[b], 1);
        int slot = lbase[b] + r;
        sval[slot]  = s | ((d & ((1 << BSH) - 1)) << 17);
        gaddr[slot] = gdelta[b] + slot;
    }
    __syncthreads();
    for (int s = tid; s < nedge; s += 256) stage[gaddr[s]] = sval[s];
}

// exclusive scan of bucket counts -> gbase[NBK+1]; row_start[N] tail
__global__ __launch_bounds__(256) void k_bucket_scan(const int* __restrict__ cursor,
                                                     int* __restrict__ gbase,
                                                     int* __restrict__ row_start,
                                                     int NBK, int E, int N) {
    __shared__ int sA[512];
    __shared__ int cnt[512];
    int tid = threadIdx.x;
    for (int i = tid; i < 512; i += 256)
        cnt[i] = (i < NBK) ? cursor[i] : 0;
    __syncthreads();
    sA[tid] = cnt[tid]; sA[tid + 256] = cnt[tid + 256];
    __syncthreads();
    for (int off = 1; off < 512; off <<= 1) {
        int r0 = sA[tid] + ((tid >= off) ? sA[tid - off] : 0);
        int r1 = sA[tid + 256] + ((tid + 256 >= off) ? sA[tid + 256 - off] : 0);
        __syncthreads();
        sA[tid] = r0; sA[tid + 256] = r1;
        __syncthreads();
    }
    for (int i = tid; i < 512; i += 256)
        if (i < NBK) gbase[i] = sA[i] - cnt[i];
    if (tid == 0) { gbase[NBK] = E; row_start[N] = E + N; }
}

// Pass 2: per-bucket fine CSR build (L2-hot window -> dense writeback)
__global__ __launch_bounds__(256) void k_build(const int* __restrict__ stage,
                                               const int* __restrict__ gbase,
                                               int* __restrict__ row_start,
                                               int* __restrict__ csr, int N) {
    __shared__ int cnt[256];
    __shared__ int lb[256];
    __shared__ int cur[256];
    __shared__ int sA[256];
    int b = blockIdx.x, tid = threadIdx.x;
    int nodes0 = b << BSH;
    int nnodes = N - nodes0; if (nnodes > 256) nnodes = 256;
    int ebase = gbase[b];
    int ecnt = gbase[b + 1] - ebase;
    const int* sbk = stage + b * BCAP;
    cnt[tid] = (tid < nnodes) ? 1 : 0;  // self loop
    __syncthreads();
    for (int e = tid; e < ecnt; e += 256) {
        int l = (sbk[e] >> 17) & 255;
        atomicAdd(&cnt[l], 1);
    }
    __syncthreads();
    int myc = cnt[tid];
    sA[tid] = myc;
    __syncthreads();
    for (int off = 1; off < 256; off <<= 1) {
        int r = sA[tid] + ((tid >= off) ? sA[tid - off] : 0);
        __syncthreads();
        sA[tid] = r;
        __syncthreads();
    }
    int gb = ebase + nodes0;
    lb[tid] = sA[tid] - myc;
    cur[tid] = 1;
    __syncthreads();
    if (tid < nnodes) {
        row_start[nodes0 + tid] = gb + lb[tid];
        csr[gb + lb[tid]] = nodes0 + tid;
    }
    __syncthreads();
    for (int e = tid; e < ecnt; e += 256) {
        int v = sbk[e];
        int l = (v >> 17) & 255;
        int src = v & 0x1FFFF;
        int r = atomicAdd(&cur[l], 1);
        csr[gb + lb[l] + r] = src;
    }
}

// h1[N,64](fp16) = x[N,128] @ W1[128,64]; 64x64 tile, 4x4/thread, fused att dots
__global__ __launch_bounds__(256) void k_gemm1(const float* __restrict__ x,
                                               const float* __restrict__ W1,
                                               const float* __restrict__ att_src,
                                               const float* __restrict__ att_dst,
                                               __half* __restrict__ h1, float* __restrict__ a_src,
                                               float* __restrict__ a_dst, int N) {
    __shared__ float ws[64][64];
    __shared__ float xs[64][68];   // TRANSPOSED: [k][node], pad 4
    int tid = threadIdx.x;
    int tc = tid & 15, tr = tid >> 4;
    int n0 = blockIdx.x * 64;
    float acc[4][4];
    #pragma unroll
    for (int a = 0; a < 4; a++)
        #pragma unroll
        for (int b = 0; b < 4; b++) acc[a][b] = 0.f;

    for (int kb = 0; kb < 2; kb++) {
        __syncthreads();
        #pragma unroll
        for (int r = 0; r < 4; r++) {
            int i = tid + 256 * r;
            int k = i >> 4, c4 = (i & 15) * 4;
            *(float4*)&ws[k][c4] = *(const float4*)&W1[(size_t)(kb * 64 + k) * 64 + c4];
        }
        #pragma unroll
        for (int r = 0; r < 4; r++) {
            int i = tid + 256 * r;
            int node = i >> 4, k4 = (i & 15) * 4;
            int n = n0 + node;
            float4 v = make_float4(0.f, 0.f, 0.f, 0.f);
            if (n < N) v = *(const float4*)&x[(size_t)n * 128 + kb * 64 + k4];
            xs[k4 + 0][node] = v.x; xs[k4 + 1][node] = v.y;
            xs[k4 + 2][node] = v.z; xs[k4 + 3][node] = v.w;
        }
        __syncthreads();
        #pragma unroll 8
        for (int k = 0; k < 64; k++) {
            float w0 = ws[k][tc * 4 + 0], w1 = ws[k][tc * 4 + 1];
            float w2 = ws[k][tc * 4 + 2], w3 = ws[k][tc * 4 + 3];
            float x0 = xs[k][tr * 4 + 0], x1 = xs[k][tr * 4 + 1];
            float x2 = xs[k][tr * 4 + 2], x3 = xs[k][tr * 4 + 3];
            acc[0][0] += x0 * w0; acc[0][1] += x0 * w1; acc[0][2] += x0 * w2; acc[0][3] += x0 * w3;
            acc[1][0] += x1 * w0; acc[1][1] += x1 * w1; acc[1][2] += x1 * w2; acc[1][3] += x1 * w3;
            acc[2][0] += x2 * w0; acc[2][1] += x2 * w1; acc[2][2] += x2 * w2; acc[2][3] += x2 * w3;
            acc[3][0] += x3 * w0; acc[3][1] += x3 * w1; acc[3][2] += x3 * w2; acc[3][3] += x3 * w3;
        }
    }
    int h = tc >> 2;
    #pragma unroll
    for (int ii = 0; ii < 4; ii++) {
        int n = n0 + tr * 4 + ii;
        float asv = 0.f, adv = 0.f;
        #pragma unroll
        for (int i = 0; i < 4; i++) {
            int cm = (tc & 3) * 4 + i;
            asv += acc[ii][i] * att_src[h * 16 + cm];
            adv += acc[ii][i] * att_dst[h * 16 + cm];
        }
        asv += __shfl_xor(asv, 1, 64); asv += __shfl_xor(asv, 2, 64);
        adv += __shfl_xor(adv, 1, 64); adv += __shfl_xor(adv, 2, 64);
        if (n < N) {
            union { __half2 h2[2]; float2 f2; } u;
            u.h2[0] = __floats2half2_rn(acc[ii][0], acc[ii][1]);
            u.h2[1] = __floats2half2_rn(acc[ii][2], acc[ii][3]);
            *(float2*)&h1[(size_t)n * 64 + tc * 4] = u.f2;
            if ((tc & 3) == 0) { a_src[n * 4 + h] = asv; a_dst[n * 4 + h] = adv; }
        }
    }
}

// layer-1 aggregation (R5 gather pattern) + ELU + FUSED layer-2 linear + att2.
// One wave per node; phase 2: all 64 lanes = channels, one edge at a time,
// 8-deep unrolled independent ushort gathers.
__global__ __launch_bounds__(256) void k_agg1(const int* __restrict__ row_start,
                                              const int* __restrict__ csr_src,
                                              const float* __restrict__ a_src,
                                              const float* __restrict__ a_dst,
                                              const __half* __restrict__ h1,
                                              const float* __restrict__ bias,
                                              const float* __restrict__ W2,
                                              const float* __restrict__ att2s_g,
                                              const float* __restrict__ att2d_g,
                                              float* __restrict__ h2,
                                              float* __restrict__ a_src2,
                                              float* __restrict__ a_dst2, int N) {
    __shared__ int   sidx[4][CAP];
    __shared__ float sval[4][CAP * 4];
    __shared__ float sout[4][64];
    __shared__ float ws2[64 * 17];   // W2 padded stride 17
    __shared__ float att2s[16], att2d[16];
    int tid = threadIdx.x;
    for (int i = tid; i < 64 * 16; i += 256) {
        int k = i >> 4, c = i & 15;
        ws2[k * 17 + c] = W2[i];
    }
    if (tid < 16) { att2s[tid] = att2s_g[tid]; att2d[tid] = att2d_g[tid]; }
    __syncthreads();

    int wave = tid >> 6, lane = tid & 63;
    int node = blockIdx.x * 4 + wave;
    bool active = node < N;
    int row = 0, deg = 0;
    float4 ad = make_float4(0.f, 0.f, 0.f, 0.f);
    if (active) {
        row = row_start[node];
        deg = row_start[node + 1] - row;
        ad = ((const float4*)a_dst)[node];
    }
    // phase 1: exp + sum (no-max: logits bounded by construction)
    float s0 = 0.f, s1 = 0.f, s2 = 0.f, s3 = 0.f;
    for (int j = lane; j < deg; j += 64) {
        int s = csr_src[row + j];
        float4 as = ((const float4*)a_src)[s];
        float e0 = __expf(LRELU(as.x + ad.x));
        float e1 = __expf(LRELU(as.y + ad.y));
        float e2 = __expf(LRELU(as.z + ad.z));
        float e3 = __expf(LRELU(as.w + ad.w));
        if (j < CAP) {
            sidx[wave][j] = s;
            *(float4*)&sval[wave][j * 4] = make_float4(e0, e1, e2, e3);
        }
        s0 += e0; s1 += e1; s2 += e2; s3 += e3;
    }
    #pragma unroll
    for (int m = 1; m < 64; m <<= 1) {
        s0 += __shfl_xor(s0, m, 64);
        s1 += __shfl_xor(s1, m, 64);
        s2 += __shfl_xor(s2, m, 64);
        s3 += __shfl_xor(s3, m, 64);
    }
    if (active) {
        int myh = lane >> 4;
        float ssv = myh == 0 ? s0 : myh == 1 ? s1 : myh == 2 ? s2 : s3;
        float adm = myh == 0 ? ad.x : myh == 1 ? ad.y : myh == 2 ? ad.z : ad.w;
        float iv = 1.f / (ssv + 1e-16f);
        float acc = 0.f, accB = 0.f;
        int dc = deg < CAP ? deg : CAP;
        int j = 0;
        for (; j + 8 <= dc; j += 8) {
            int t0 = sidx[wave][j + 0], t1 = sidx[wave][j + 1];
            int t2 = sidx[wave][j + 2], t3 = sidx[wave][j + 3];
            int t4 = sidx[wave][j + 4], t5 = sidx[wave][j + 5];
            int t6 = sidx[wave][j + 6], t7 = sidx[wave][j + 7];
            float e0 = sval[wave][(j + 0) * 4 + myh], e1 = sval[wave][(j + 1) * 4 + myh];
            float e2 = sval[wave][(j + 2) * 4 + myh], e3 = sval[wave][(j + 3) * 4 + myh];
            float e4 = sval[wave][(j + 4) * 4 + myh], e5 = sval[wave][(j + 5) * 4 + myh];
            float e6 = sval[wave][(j + 6) * 4 + myh], e7 = sval[wave][(j + 7) * 4 + myh];
            float g0 = __half2float(h1[(size_t)t0 * 64 + lane]);
            float g1 = __half2float(h1[(size_t)t1 * 64 + lane]);
            float g2 = __half2float(h1[(size_t)t2 * 64 + lane]);
            float g3 = __half2float(h1[(size_t)t3 * 64 + lane]);
            float g4 = __half2float(h1[(size_t)t4 * 64 + lane]);
            float g5 = __half2float(h1[(size_t)t5 * 64 + lane]);
            float g6 = __half2float(h1[(size_t)t6 * 64 + lane]);
            float g7 = __half2float(h1[(size_t)t7 * 64 + lane]);
            acc  += e0 * g0 + e2 * g2 + e4 * g4 + e6 * g6;
            accB += e1 * g1 + e3 * g3 + e5 * g5 + e7 * g7;
        }
        for (; j + 4 <= dc; j += 4) {
            int t0 = sidx[wave][j + 0], t1 = sidx[wave][j + 1];
            int t2 = sidx[wave][j + 2], t3 = sidx[wave][j + 3];
            float e0 = sval[wave][(j + 0) * 4 + myh], e1 = sval[wave][(j + 1) * 4 + myh];
            float e2 = sval[wave][(j + 2) * 4 + myh], e3 = sval[wave][(j + 3) * 4 + myh];
            float g0 = __half2float(h1[(size_t)t0 * 64 + lane]);
            float g1 = __half2float(h1[(size_t)t1 * 64 + lane]);
            float g2 = __half2float(h1[(size_t)t2 * 64 + lane]);
            float g3 = __half2float(h1[(size_t)t3 * 64 + lane]);
            acc  += e0 * g0 + e2 * g2;
            accB += e1 * g1 + e3 * g3;
        }
        for (; j < dc; j++)
            acc += sval[wave][j * 4 + myh] * __half2float(h1[(size_t)sidx[wave][j] * 64 + lane]);
        for (; j < deg; j++) {  // deg > CAP fallback
            int s = csr_src[row + j];
            float e = __expf(LRELU(a_src[s * 4 + myh] + adm));
            acc += e * __half2float(h1[(size_t)s * 64 + lane]);
        }
        acc = (acc + accB) * iv;
        float o = acc + bias[lane];
        o = (o > 0.f) ? o : (__expf(o) - 1.f);  // ELU
        sout[wave][lane] = o;                   // lane == channel; wave-coherent
        // fused gemm2: h2[c2] = sum_k out1[k]*W2[k][c2]
        int c2 = lane & 15, kc = lane >> 4;
        float dot = 0.f;
        #pragma unroll
        for (int i = 0; i < 16; i++)
            dot += sout[wave][kc * 16 + i] * ws2[(kc * 16 + i) * 17 + c2];
        dot += __shfl_xor(dot, 16, 64);
        dot += __shfl_xor(dot, 32, 64);
        if (kc == 0) h2[(size_t)node * 16 + c2] = dot;
        float asv = dot * att2s[c2], adv = dot * att2d[c2];
        #pragma unroll
        for (int m = 1; m < 16; m <<= 1) {
            asv += __shfl_xor(asv, m, 64);
            adv += __shfl_xor(adv, m, 64);
        }
        if (lane == 0) { a_src2[node] = asv; a_dst2[node] = adv; }
    }
}

// layer-2 aggregation + bias + log_softmax (R5 gather pattern)
__global__ __launch_bounds__(256) void k_agg2(const int* __restrict__ row_start,
                                              const int* __restrict__ csr_src,
                                              const float* __restrict__ a_src,
                                              const float* __restrict__ a_dst,
                                              const float* __restrict__ h2,
                                              const float* __restrict__ bias,
                                              float* __restrict__ out, int N) {
    __shared__ int   sidx[4][CAP];
    __shared__ float sval[4][CAP];
    int wave = threadIdx.x >> 6, lane = threadIdx.x & 63;
    int node = blockIdx.x * 4 + wave;
    if (node >= N) return;
    int row = row_start[node];
    int deg = row_start[node + 1] - row;
    float ad = a_dst[node];
    float sh = 0.f;
    for (int j = lane; j < deg; j += 64) {
        int s = csr_src[row + j];
        float e = __expf(LRELU(a_src[s] + ad));
        if (j < CAP) { sidx[wave][j] = s; sval[wave][j] = e; }
        sh += e;
    }
    #pragma unroll
    for (int m = 1; m < 64; m <<= 1) sh += __shfl_xor(sh, m, 64);
    float iv = 1.f / (sh + 1e-16f);
    int c = lane & 15, sub = lane >> 4;
    float acc = 0.f, acc2 = 0.f;
    int dc = deg < CAP ? deg : CAP;
    int j = sub;
    for (; j + 4 < dc; j += 8) {
        int t0 = sidx[wave][j], t1 = sidx[wave][j + 4];
        float e0 = sval[wave][j], e1 = sval[wave][j + 4];
        float g0 = h2[(size_t)t0 * 16 + c], g1 = h2[(size_t)t1 * 16 + c];
        acc += e0 * g0; acc2 += e1 * g1;
    }
    for (; j < deg; j += 4) {
        int s; float e;
        if (j < dc) { s = sidx[wave][j]; e = sval[wave][j]; }
        else { s = csr_src[row + j]; e = __expf(LRELU(a_src[s] + ad)); }
        acc += e * h2[(size_t)s * 16 + c];
    }
    acc += acc2;
    acc += __shfl_xor(acc, 16, 64);
    acc += __shfl_xor(acc, 32, 64);
    float val = acc * iv + bias[c];
    float mx = val;
    #pragma unroll
    for (int m = 1; m < 16; m <<= 1) mx = fmaxf(mx, __shfl_xor(mx, m, 64));
    float se = __expf(val - mx);
    #pragma unroll
    for (int m = 1; m < 16; m <<= 1) se += __shfl_xor(se, m, 64);
    float o = val - mx - __logf(se);
    if (sub == 0) out[(size_t)node * 16 + c] = o;
}

extern "C" void kernel_launch(void* const* d_in, const int* in_sizes, int n_in,
                              void* d_out, int out_size, void* d_ws, size_t ws_size,
                              hipStream_t stream) {
    const float* x        = (const float*)d_in[0];
    const int*   ei       = (const int*)d_in[1];
    const float* W1       = (const float*)d_in[2];
    const float* att_src1 = (const float*)d_in[3];
    const float* att_dst1 = (const float*)d_in[4];
    const float* bias1    = (const float*)d_in[5];
    const float* W2       = (const float*)d_in[6];
    const float* att_src2 = (const float*)d_in[7];
    const float* att_dst2 = (const float*)d_in[8];
    const float* bias2    = (const float*)d_in[9];
    float* out = (float*)d_out;

    const int N = in_sizes[0] / 128;
    const int E = in_sizes[1] / 2;
    const int NBK = (N + 255) >> BSH;

    char* p = (char*)d_ws;
    auto alloc = [&](size_t bytes) -> void* {
        void* r = (void*)p;
        p += (bytes + 255) & ~(size_t)255;
        return r;
    };
    __half* h1     = (__half*)alloc((size_t)N * 64 * 2);
    float* h2      = (float*)alloc((size_t)N * 16 * 4);
    float* a_src1  = (float*)alloc((size_t)N * 4 * 4);
    float* a_dst1  = (float*)alloc((size_t)N * 4 * 4);
    float* a_src2  = (float*)alloc((size_t)N * 4);
    float* a_dst2  = (float*)alloc((size_t)N * 4);
    int*   row_st  = (int*)alloc((size_t)(N + 1) * 4);
    int*   csr     = (int*)alloc((size_t)(E + N) * 4);
    int*   stage   = (int*)alloc((size_t)NBK * BCAP * 4);
    int*   cursor  = (int*)alloc((size_t)NBK * 4);
    int*   gbase   = (int*)alloc((size_t)(NBK + 1) * 4);
    (void)ws_size; (void)n_in; (void)out_size;

    hipMemsetAsync(cursor, 0, (size_t)NBK * 4, stream);
    k_scatter<<<(E + CHK - 1) / CHK, 256, 0, stream>>>(ei, cursor, stage, E, NBK);
    k_bucket_scan<<<1, 256, 0, stream>>>(cursor, gbase, row_st, NBK, E, N);
    k_build<<<NBK, 256, 0, stream>>>(stage, gbase, row_st, csr, N);
    k_gemm1<<<(N + 63) / 64, 256, 0, stream>>>(x, W1, att_src1, att_dst1, h1, a_src1, a_dst1, N);
    k_agg1<<<(N + 3) / 4, 256, 0, stream>>>(row_st, csr, a_src1, a_dst1, h1, bias1,
                                            W2, att_src2, att_dst2, h2, a_src2, a_dst2, N);
    k_agg2<<<(N + 3) / 4, 256, 0, stream>>>(row_st, csr, a_src2, a_dst2, h2, bias2, out, N);
}

// Round 8
// 294.542 us; speedup vs baseline: 1.0312x; 1.0312x over previous
//
#include <hip/hip_runtime.h>
#include <hip/hip_fp16.h>
#include <hip/hip_bf16.h>
#include <math.h>

// GAT 2-layer forward, MI355X. FP32 in/out, int32 edge_index.
// R8: full revert to R5 structure (fusion was a measured net loss) +
// MFMA-bf16 gemm1 (16x16x32, A from global, W1^T bf16 in LDS).

#define LRELU(v) ((v) > 0.f ? (v) : 0.2f * (v))
#define CAP 128          // agg LDS edge cache per node
#define BSH 8            // 256 nodes per bucket
#define BCAP 5120        // staged capacity per bucket
#define CHK 2048         // edges per k_scatter block

typedef __attribute__((ext_vector_type(8))) short short8;
typedef __attribute__((ext_vector_type(4))) float float4v;

static __device__ __forceinline__ short f2bf(float f) {
    __hip_bfloat16 b = __float2bfloat16(f);
    return *reinterpret_cast<short*>(&b);
}

// Pass 1: bin edges by dst bucket, stage reordered in LDS, flush dense runs.
__global__ __launch_bounds__(256) void k_scatter(const int* __restrict__ ei, int* __restrict__ cursor,
                                                 int* __restrict__ stage, int E, int NBK) {
    __shared__ int sval[CHK];
    __shared__ int gaddr[CHK];
    __shared__ int sdst[CHK];
    __shared__ int hist[512];
    __shared__ int lbase[512];
    __shared__ int cnt2[512];
    __shared__ int gdelta[512];
    __shared__ int sA[512];
    int tid = threadIdx.x;
    int e0 = blockIdx.x * CHK;
    int nedge = E - e0; if (nedge > CHK) nedge = CHK;

    for (int i = tid; i < 512; i += 256) { hist[i] = 0; cnt2[i] = 0; }
    __syncthreads();
    for (int j = tid; j < nedge; j += 256) {
        int d = ei[E + e0 + j];
        sdst[j] = d;
        atomicAdd(&hist[d >> BSH], 1);
    }
    __syncthreads();
    sA[tid] = hist[tid]; sA[tid + 256] = hist[tid + 256];
    __syncthreads();
    for (int off = 1; off < 512; off <<= 1) {
        int r0 = sA[tid] + ((tid >= off) ? sA[tid - off] : 0);
        int r1 = sA[tid + 256] + ((tid + 256 >= off) ? sA[tid + 256 - off] : 0);
        __syncthreads();
        sA[tid] = r0; sA[tid + 256] = r1;
        __syncthreads();
    }
    for (int i = tid; i < 512; i += 256) lbase[i] = sA[i] - hist[i];
    __syncthreads();
    for (int b = tid; b < NBK; b += 256) {
        int c = hist[b];
        if (c > 0) {
            int rel = atomicAdd(&cursor[b], c);
            gdelta[b] = b * BCAP + rel - lbase[b];
        }
    }
    __syncthreads();
    for (int j = tid; j < nedge; j += 256) {
        int s = ei[e0 + j];
        int d = sdst[j];
        int b = d >> BSH;
        int r = atomicAdd(&cnt2[b], 1);
        int slot = lbase[b] + r;
        sval[slot]  = s | ((d & ((1 << BSH) - 1)) << 17);
        gaddr[slot] = gdelta[b] + slot;
    }
    __syncthreads();
    for (int s = tid; s < nedge; s += 256) stage[gaddr[s]] = sval[s];
}

// exclusive scan of bucket counts -> gbase[NBK+1]; row_start[N] tail
__global__ __launch_bounds__(256) void k_bucket_scan(const int* __restrict__ cursor,
                                                     int* __restrict__ gbase,
                                                     int* __restrict__ row_start,
                                                     int NBK, int E, int N) {
    __shared__ int sA[512];
    __shared__ int cnt[512];
    int tid = threadIdx.x;
    for (int i = tid; i < 512; i += 256)
        cnt[i] = (i < NBK) ? cursor[i] : 0;
    __syncthreads();
    sA[tid] = cnt[tid]; sA[tid + 256] = cnt[tid + 256];
    __syncthreads();
    for (int off = 1; off < 512; off <<= 1) {
        int r0 = sA[tid] + ((tid >= off) ? sA[tid - off] : 0);
        int r1 = sA[tid + 256] + ((tid + 256 >= off) ? sA[tid + 256 - off] : 0);
        __syncthreads();
        sA[tid] = r0; sA[tid + 256] = r1;
        __syncthreads();
    }
    for (int i = tid; i < 512; i += 256)
        if (i < NBK) gbase[i] = sA[i] - cnt[i];
    if (tid == 0) { gbase[NBK] = E; row_start[N] = E + N; }
}

// Pass 2: per-bucket fine CSR build (L2-hot window -> dense writeback)
__global__ __launch_bounds__(256) void k_build(const int* __restrict__ stage,
                                               const int* __restrict__ gbase,
                                               int* __restrict__ row_start,
                                               int* __restrict__ csr, int N) {
    __shared__ int cnt[256];
    __shared__ int lb[256];
    __shared__ int cur[256];
    __shared__ int sA[256];
    int b = blockIdx.x, tid = threadIdx.x;
    int nodes0 = b << BSH;
    int nnodes = N - nodes0; if (nnodes > 256) nnodes = 256;
    int ebase = gbase[b];
    int ecnt = gbase[b + 1] - ebase;
    const int* sbk = stage + b * BCAP;
    cnt[tid] = (tid < nnodes) ? 1 : 0;  // self loop
    __syncthreads();
    for (int e = tid; e < ecnt; e += 256) {
        int l = (sbk[e] >> 17) & 255;
        atomicAdd(&cnt[l], 1);
    }
    __syncthreads();
    int myc = cnt[tid];
    sA[tid] = myc;
    __syncthreads();
    for (int off = 1; off < 256; off <<= 1) {
        int r = sA[tid] + ((tid >= off) ? sA[tid - off] : 0);
        __syncthreads();
        sA[tid] = r;
        __syncthreads();
    }
    int gb = ebase + nodes0;
    lb[tid] = sA[tid] - myc;
    cur[tid] = 1;
    __syncthreads();
    if (tid < nnodes) {
        row_start[nodes0 + tid] = gb + lb[tid];
        csr[gb + lb[tid]] = nodes0 + tid;
    }
    __syncthreads();
    for (int e = tid; e < ecnt; e += 256) {
        int v = sbk[e];
        int l = (v >> 17) & 255;
        int src = v & 0x1FFFF;
        int r = atomicAdd(&cur[l], 1);
        csr[gb + lb[l] + r] = src;
    }
}

// h1[N,64](fp16) = x[N,128] @ W1[128,64] via MFMA 16x16x32 bf16.
// Block = 4 waves; wave tile = 16 nodes x 64 cols x K=128.
// A: straight from global (lane m=lane&15 -> node, k=(lane>>4)*8+j).
// B: W1^T bf16 in LDS, stride 136 shorts (2-way-conflict-free b128 reads).
// C: col=lane&15, row=(lane>>4)*4+reg  [m89-verified].
// Epilogue: h1 fp16 store + fused a_src1/a_dst1 head dots (m-bit butterfly).
__global__ __launch_bounds__(256) void k_gemm1(const float* __restrict__ x,
                                               const float* __restrict__ W1,
                                               const float* __restrict__ att_src,
                                               const float* __restrict__ att_dst,
                                               __half* __restrict__ h1, float* __restrict__ a_src,
                                               float* __restrict__ a_dst, int N) {
    __shared__ short wt[64 * 136];   // wt[c*136 + k] = bf16(W1[k][c])
    int tid = threadIdx.x;
    for (int i = tid; i < 128 * 64; i += 256) {
        int k = i >> 6, c = i & 63;
        wt[c * 136 + k] = f2bf(W1[i]);
    }
    __syncthreads();
    int wave = tid >> 6, lane = tid & 63;
    int m = lane & 15, q = lane >> 4;
    int nbase = blockIdx.x * 64 + wave * 16;
    int anode = nbase + m;
    bool rowok = anode < N;
    const float* xrow = x + (size_t)(rowok ? anode : 0) * 128 + q * 8;

    float4v acc[4];
    #pragma unroll
    for (int ct = 0; ct < 4; ct++)
        #pragma unroll
        for (int r = 0; r < 4; r++) acc[ct][r] = 0.f;

    #pragma unroll
    for (int kc = 0; kc < 4; kc++) {
        float4 u0 = make_float4(0.f, 0.f, 0.f, 0.f), u1 = u0;
        if (rowok) {
            u0 = *(const float4*)(xrow + kc * 32);
            u1 = *(const float4*)(xrow + kc * 32 + 4);
        }
        short8 af;
        af[0] = f2bf(u0.x); af[1] = f2bf(u0.y); af[2] = f2bf(u0.z); af[3] = f2bf(u0.w);
        af[4] = f2bf(u1.x); af[5] = f2bf(u1.y); af[6] = f2bf(u1.z); af[7] = f2bf(u1.w);
        #pragma unroll
        for (int ct = 0; ct < 4; ct++) {
            short8 bf = *(const short8*)&wt[(ct * 16 + m) * 136 + kc * 32 + q * 8];
            acc[ct] = __builtin_amdgcn_mfma_f32_16x16x32_bf16(af, bf, acc[ct], 0, 0, 0);
        }
    }
    // epilogue: stores + att dots. acc[ct][r] = h1[nbase+q*4+r][ct*16+m]
    #pragma unroll
    for (int ct = 0; ct < 4; ct++) {
        float ats = att_src[ct * 16 + m];
        float atd = att_dst[ct * 16 + m];
        #pragma unroll
        for (int r = 0; r < 4; r++) {
            int n = nbase + q * 4 + r;
            float v = acc[ct][r];
            if (n < N) h1[(size_t)n * 64 + ct * 16 + m] = __float2half(v);
            float asv = v * ats, adv = v * atd;
            #pragma unroll
            for (int mm = 1; mm < 16; mm <<= 1) {
                asv += __shfl_xor(asv, mm, 64);
                adv += __shfl_xor(adv, mm, 64);
            }
            if (m == 0 && n < N) {
                a_src[n * 4 + ct] = asv;
                a_dst[n * 4 + ct] = adv;
            }
        }
    }
}

// layer-1 aggregation: one wave per node, no-max softmax, single exp pass (R5)
__global__ __launch_bounds__(256) void k_agg1(const int* __restrict__ row_start,
                                              const int* __restrict__ csr_src,
                                              const float* __restrict__ a_src,
                                              const float* __restrict__ a_dst,
                                              const __half* __restrict__ h1,
                                              const float* __restrict__ bias,
                                              float* __restrict__ out1, int N) {
    __shared__ int   sidx[4][CAP];
    __shared__ float sval[4][CAP * 4];
    int wave = threadIdx.x >> 6, lane = threadIdx.x & 63;
    int node = blockIdx.x * 4 + wave;
    if (node >= N) return;
    int row = row_start[node];
    int deg = row_start[node + 1] - row;
    float4 ad = ((const float4*)a_dst)[node];
    float s0 = 0.f, s1 = 0.f, s2 = 0.f, s3 = 0.f;
    for (int j = lane; j < deg; j += 64) {
        int s = csr_src[row + j];
        float4 as = ((const float4*)a_src)[s];
        float e0 = __expf(LRELU(as.x + ad.x));
        float e1 = __expf(LRELU(as.y + ad.y));
        float e2 = __expf(LRELU(as.z + ad.z));
        float e3 = __expf(LRELU(as.w + ad.w));
        if (j < CAP) {
            sidx[wave][j] = s;
            *(float4*)&sval[wave][j * 4] = make_float4(e0, e1, e2, e3);
        }
        s0 += e0; s1 += e1; s2 += e2; s3 += e3;
    }
    #pragma unroll
    for (int m = 1; m < 64; m <<= 1) {
        s0 += __shfl_xor(s0, m, 64);
        s1 += __shfl_xor(s1, m, 64);
        s2 += __shfl_xor(s2, m, 64);
        s3 += __shfl_xor(s3, m, 64);
    }
    int myh = lane >> 4;
    float ssv = myh == 0 ? s0 : myh == 1 ? s1 : myh == 2 ? s2 : s3;
    float adm = myh == 0 ? ad.x : myh == 1 ? ad.y : myh == 2 ? ad.z : ad.w;
    float iv = 1.f / (ssv + 1e-16f);
    float acc = 0.f, accB = 0.f;
    int dc = deg < CAP ? deg : CAP;
    int j = 0;
    for (; j + 8 <= dc; j += 8) {
        int t0 = sidx[wave][j + 0], t1 = sidx[wave][j + 1];
        int t2 = sidx[wave][j + 2], t3 = sidx[wave][j + 3];
        int t4 = sidx[wave][j + 4], t5 = sidx[wave][j + 5];
        int t6 = sidx[wave][j + 6], t7 = sidx[wave][j + 7];
        float e0 = sval[wave][(j + 0) * 4 + myh], e1 = sval[wave][(j + 1) * 4 + myh];
        float e2 = sval[wave][(j + 2) * 4 + myh], e3 = sval[wave][(j + 3) * 4 + myh];
        float e4 = sval[wave][(j + 4) * 4 + myh], e5 = sval[wave][(j + 5) * 4 + myh];
        float e6 = sval[wave][(j + 6) * 4 + myh], e7 = sval[wave][(j + 7) * 4 + myh];
        float g0 = __half2float(h1[(size_t)t0 * 64 + lane]);
        float g1 = __half2float(h1[(size_t)t1 * 64 + lane]);
        float g2 = __half2float(h1[(size_t)t2 * 64 + lane]);
        float g3 = __half2float(h1[(size_t)t3 * 64 + lane]);
        float g4 = __half2float(h1[(size_t)t4 * 64 + lane]);
        float g5 = __half2float(h1[(size_t)t5 * 64 + lane]);
        float g6 = __half2float(h1[(size_t)t6 * 64 + lane]);
        float g7 = __half2float(h1[(size_t)t7 * 64 + lane]);
        acc  += e0 * g0 + e2 * g2 + e4 * g4 + e6 * g6;
        accB += e1 * g1 + e3 * g3 + e5 * g5 + e7 * g7;
    }
    for (; j + 4 <= dc; j += 4) {
        int t0 = sidx[wave][j + 0], t1 = sidx[wave][j + 1];
        int t2 = sidx[wave][j + 2], t3 = sidx[wave][j + 3];
        float e0 = sval[wave][(j + 0) * 4 + myh], e1 = sval[wave][(j + 1) * 4 + myh];
        float e2 = sval[wave][(j + 2) * 4 + myh], e3 = sval[wave][(j + 3) * 4 + myh];
        float g0 = __half2float(h1[(size_t)t0 * 64 + lane]);
        float g1 = __half2float(h1[(size_t)t1 * 64 + lane]);
        float g2 = __half2float(h1[(size_t)t2 * 64 + lane]);
        float g3 = __half2float(h1[(size_t)t3 * 64 + lane]);
        acc  += e0 * g0 + e2 * g2;
        accB += e1 * g1 + e3 * g3;
    }
    for (; j < dc; j++)
        acc += sval[wave][j * 4 + myh] * __half2float(h1[(size_t)sidx[wave][j] * 64 + lane]);
    for (; j < deg; j++) {
        int s = csr_src[row + j];
        float e = __expf(LRELU(a_src[s * 4 + myh] + adm));
        acc += e * __half2float(h1[(size_t)s * 64 + lane]);
    }
    acc = (acc + accB) * iv;
    float o = acc + bias[lane];
    o = (o > 0.f) ? o : (__expf(o) - 1.f);  // ELU
    out1[(size_t)node * 64 + lane] = o;
}

// h2[N,16] = out1[N,64] @ W2[64,16]; fused att2 dots (R5)
__global__ __launch_bounds__(256) void k_gemm2(const float* __restrict__ out1,
                                               const float* __restrict__ W2,
                                               const float* __restrict__ att_src,
                                               const float* __restrict__ att_dst,
                                               float* __restrict__ h2, float* __restrict__ a_src,
                                               float* __restrict__ a_dst, int N) {
    __shared__ float ws[64 * 16];
    __shared__ float xs[16 * 65];
    int tid = threadIdx.x;
    for (int i = tid; i < 64 * 16; i += 256) ws[i] = W2[i];
    int n0 = blockIdx.x * 16;
    for (int i = tid; i < 16 * 64; i += 256) {
        int r = i >> 6, c = i & 63;
        int n = n0 + r;
        xs[r * 65 + c] = (n < N) ? out1[(size_t)n * 64 + c] : 0.f;
    }
    __syncthreads();
    int nl = tid >> 4, c = tid & 15;
    int n = n0 + nl;
    float acc = 0.f;
    #pragma unroll
    for (int k = 0; k < 64; k++) acc += xs[nl * 65 + k] * ws[k * 16 + c];
    float asv = acc * att_src[c];
    float adv = acc * att_dst[c];
    #pragma unroll
    for (int m = 1; m < 16; m <<= 1) {
        asv += __shfl_xor(asv, m, 64);
        adv += __shfl_xor(adv, m, 64);
    }
    if (n < N) {
        h2[(size_t)n * 16 + c] = acc;
        if (c == 0) { a_src[n] = asv; a_dst[n] = adv; }
    }
}

// layer-2 aggregation + bias + log_softmax (R5)
__global__ __launch_bounds__(256) void k_agg2(const int* __restrict__ row_start,
                                              const int* __restrict__ csr_src,
                                              const float* __restrict__ a_src,
                                              const float* __restrict__ a_dst,
                                              const float* __restrict__ h2,
                                              const float* __restrict__ bias,
                                              float* __restrict__ out, int N) {
    __shared__ int   sidx[4][CAP];
    __shared__ float sval[4][CAP];
    int wave = threadIdx.x >> 6, lane = threadIdx.x & 63;
    int node = blockIdx.x * 4 + wave;
    if (node >= N) return;
    int row = row_start[node];
    int deg = row_start[node + 1] - row;
    float ad = a_dst[node];
    float sh = 0.f;
    for (int j = lane; j < deg; j += 64) {
        int s = csr_src[row + j];
        float e = __expf(LRELU(a_src[s] + ad));
        if (j < CAP) { sidx[wave][j] = s; sval[wave][j] = e; }
        sh += e;
    }
    #pragma unroll
    for (int m = 1; m < 64; m <<= 1) sh += __shfl_xor(sh, m, 64);
    float iv = 1.f / (sh + 1e-16f);
    int c = lane & 15, sub = lane >> 4;
    float acc = 0.f, acc2 = 0.f;
    int dc = deg < CAP ? deg : CAP;
    int j = sub;
    for (; j + 4 < dc; j += 8) {
        int t0 = sidx[wave][j], t1 = sidx[wave][j + 4];
        float e0 = sval[wave][j], e1 = sval[wave][j + 4];
        float g0 = h2[(size_t)t0 * 16 + c], g1 = h2[(size_t)t1 * 16 + c];
        acc += e0 * g0; acc2 += e1 * g1;
    }
    for (; j < deg; j += 4) {
        int s; float e;
        if (j < dc) { s = sidx[wave][j]; e = sval[wave][j]; }
        else { s = csr_src[row + j]; e = __expf(LRELU(a_src[s] + ad)); }
        acc += e * h2[(size_t)s * 16 + c];
    }
    acc += acc2;
    acc += __shfl_xor(acc, 16, 64);
    acc += __shfl_xor(acc, 32, 64);
    float val = acc * iv + bias[c];
    float mx = val;
    #pragma unroll
    for (int m = 1; m < 16; m <<= 1) mx = fmaxf(mx, __shfl_xor(mx, m, 64));
    float se = __expf(val - mx);
    #pragma unroll
    for (int m = 1; m < 16; m <<= 1) se += __shfl_xor(se, m, 64);
    float o = val - mx - __logf(se);
    if (sub == 0) out[(size_t)node * 16 + c] = o;
}

extern "C" void kernel_launch(void* const* d_in, const int* in_sizes, int n_in,
                              void* d_out, int out_size, void* d_ws, size_t ws_size,
                              hipStream_t stream) {
    const float* x        = (const float*)d_in[0];
    const int*   ei       = (const int*)d_in[1];
    const float* W1       = (const float*)d_in[2];
    const float* att_src1 = (const float*)d_in[3];
    const float* att_dst1 = (const float*)d_in[4];
    const float* bias1    = (const float*)d_in[5];
    const float* W2       = (const float*)d_in[6];
    const float* att_src2 = (const float*)d_in[7];
    const float* att_dst2 = (const float*)d_in[8];
    const float* bias2    = (const float*)d_in[9];
    float* out = (float*)d_out;

    const int N = in_sizes[0] / 128;
    const int E = in_sizes[1] / 2;
    const int NBK = (N + 255) >> BSH;

    char* p = (char*)d_ws;
    auto alloc = [&](size_t bytes) -> void* {
        void* r = (void*)p;
        p += (bytes + 255) & ~(size_t)255;
        return r;
    };
    __half* h1     = (__half*)alloc((size_t)N * 64 * 2);
    float* out1    = (float*)alloc((size_t)N * 64 * 4);
    float* h2      = (float*)alloc((size_t)N * 16 * 4);
    float* a_src1  = (float*)alloc((size_t)N * 4 * 4);
    float* a_dst1  = (float*)alloc((size_t)N * 4 * 4);
    float* a_src2  = (float*)alloc((size_t)N * 4);
    float* a_dst2  = (float*)alloc((size_t)N * 4);
    int*   row_st  = (int*)alloc((size_t)(N + 1) * 4);
    int*   csr     = (int*)alloc((size_t)(E + N) * 4);
    int*   stage   = (int*)alloc((size_t)NBK * BCAP * 4);
    int*   cursor  = (int*)alloc((size_t)NBK * 4);
    int*   gbase   = (int*)alloc((size_t)(NBK + 1) * 4);
    (void)ws_size; (void)n_in; (void)out_size;

    hipMemsetAsync(cursor, 0, (size_t)NBK * 4, stream);
    k_scatter<<<(E + CHK - 1) / CHK, 256, 0, stream>>>(ei, cursor, stage, E, NBK);
    k_bucket_scan<<<1, 256, 0, stream>>>(cursor, gbase, row_st, NBK, E, N);
    k_build<<<NBK, 256, 0, stream>>>(stage, gbase, row_st, csr, N);
    k_gemm1<<<(N + 63) / 64, 256, 0, stream>>>(x, W1, att_src1, att_dst1, h1, a_src1, a_dst1, N);
    k_agg1<<<(N + 3) / 4, 256, 0, stream>>>(row_st, csr, a_src1, a_dst1, h1, bias1, out1, N);
    k_gemm2<<<(N + 15) / 16, 256, 0, stream>>>(out1, W2, att_src2, att_dst2, h2, a_src2, a_dst2, N);
    k_agg2<<<(N + 3) / 4, 256, 0, stream>>>(row_st, csr, a_src2, a_dst2, h2, bias2, out, N);
}

// Round 9
// 281.965 us; speedup vs baseline: 1.0772x; 1.0446x over previous
//
#include <hip/hip_runtime.h>
#include <hip/hip_fp16.h>
#include <hip/hip_bf16.h>
#include <math.h>

// GAT 2-layer forward, MI355X. FP32 in/out, int32 edge_index.
// R9: gemm1 att-dots folded into MFMA via precomputed Wa/Wb columns
// (epilogue shuffle-free); agg2 2-nodes-per-wave; agg1/CSR from R8 (proven).

#define LRELU(v) ((v) > 0.f ? (v) : 0.2f * (v))
#define CAP 128          // agg1 LDS edge cache per node
#define BSH 8            // 256 nodes per bucket
#define BCAP 5120        // staged capacity per bucket
#define CHK 2048         // edges per k_scatter block

typedef __attribute__((ext_vector_type(8))) short short8;
typedef __attribute__((ext_vector_type(4))) float float4v;

static __device__ __forceinline__ short f2bf(float f) {
    __hip_bfloat16 b = __float2bfloat16(f);
    return *reinterpret_cast<short*>(&b);
}

// Pass 1: bin edges by dst bucket, stage reordered in LDS, flush dense runs.
__global__ __launch_bounds__(256) void k_scatter(const int* __restrict__ ei, int* __restrict__ cursor,
                                                 int* __restrict__ stage, int E, int NBK) {
    __shared__ int sval[CHK];
    __shared__ int gaddr[CHK];
    __shared__ int sdst[CHK];
    __shared__ int hist[512];
    __shared__ int lbase[512];
    __shared__ int cnt2[512];
    __shared__ int gdelta[512];
    __shared__ int sA[512];
    int tid = threadIdx.x;
    int e0 = blockIdx.x * CHK;
    int nedge = E - e0; if (nedge > CHK) nedge = CHK;

    for (int i = tid; i < 512; i += 256) { hist[i] = 0; cnt2[i] = 0; }
    __syncthreads();
    for (int j = tid; j < nedge; j += 256) {
        int d = ei[E + e0 + j];
        sdst[j] = d;
        atomicAdd(&hist[d >> BSH], 1);
    }
    __syncthreads();
    sA[tid] = hist[tid]; sA[tid + 256] = hist[tid + 256];
    __syncthreads();
    for (int off = 1; off < 512; off <<= 1) {
        int r0 = sA[tid] + ((tid >= off) ? sA[tid - off] : 0);
        int r1 = sA[tid + 256] + ((tid + 256 >= off) ? sA[tid + 256 - off] : 0);
        __syncthreads();
        sA[tid] = r0; sA[tid + 256] = r1;
        __syncthreads();
    }
    for (int i = tid; i < 512; i += 256) lbase[i] = sA[i] - hist[i];
    __syncthreads();
    for (int b = tid; b < NBK; b += 256) {
        int c = hist[b];
        if (c > 0) {
            int rel = atomicAdd(&cursor[b], c);
            gdelta[b] = b * BCAP + rel - lbase[b];
        }
    }
    __syncthreads();
    for (int j = tid; j < nedge; j += 256) {
        int s = ei[e0 + j];
        int d = sdst[j];
        int b = d >> BSH;
        int r = atomicAdd(&cnt2[b], 1);
        int slot = lbase[b] + r;
        sval[slot]  = s | ((d & ((1 << BSH) - 1)) << 17);
        gaddr[slot] = gdelta[b] + slot;
    }
    __syncthreads();
    for (int s = tid; s < nedge; s += 256) stage[gaddr[s]] = sval[s];
}

// exclusive scan of bucket counts -> gbase[NBK+1]; row_start[N] tail
__global__ __launch_bounds__(256) void k_bucket_scan(const int* __restrict__ cursor,
                                                     int* __restrict__ gbase,
                                                     int* __restrict__ row_start,
                                                     int NBK, int E, int N) {
    __shared__ int sA[512];
    __shared__ int cnt[512];
    int tid = threadIdx.x;
    for (int i = tid; i < 512; i += 256)
        cnt[i] = (i < NBK) ? cursor[i] : 0;
    __syncthreads();
    sA[tid] = cnt[tid]; sA[tid + 256] = cnt[tid + 256];
    __syncthreads();
    for (int off = 1; off < 512; off <<= 1) {
        int r0 = sA[tid] + ((tid >= off) ? sA[tid - off] : 0);
        int r1 = sA[tid + 256] + ((tid + 256 >= off) ? sA[tid + 256 - off] : 0);
        __syncthreads();
        sA[tid] = r0; sA[tid + 256] = r1;
        __syncthreads();
    }
    for (int i = tid; i < 512; i += 256)
        if (i < NBK) gbase[i] = sA[i] - cnt[i];
    if (tid == 0) { gbase[NBK] = E; row_start[N] = E + N; }
}

// Pass 2: per-bucket fine CSR build (L2-hot window -> dense writeback)
__global__ __launch_bounds__(256) void k_build(const int* __restrict__ stage,
                                               const int* __restrict__ gbase,
                                               int* __restrict__ row_start,
                                               int* __restrict__ csr, int N) {
    __shared__ int cnt[256];
    __shared__ int lb[256];
    __shared__ int cur[256];
    __shared__ int sA[256];
    int b = blockIdx.x, tid = threadIdx.x;
    int nodes0 = b << BSH;
    int nnodes = N - nodes0; if (nnodes > 256) nnodes = 256;
    int ebase = gbase[b];
    int ecnt = gbase[b + 1] - ebase;
    const int* sbk = stage + b * BCAP;
    cnt[tid] = (tid < nnodes) ? 1 : 0;  // self loop
    __syncthreads();
    for (int e = tid; e < ecnt; e += 256) {
        int l = (sbk[e] >> 17) & 255;
        atomicAdd(&cnt[l], 1);
    }
    __syncthreads();
    int myc = cnt[tid];
    sA[tid] = myc;
    __syncthreads();
    for (int off = 1; off < 256; off <<= 1) {
        int r = sA[tid] + ((tid >= off) ? sA[tid - off] : 0);
        __syncthreads();
        sA[tid] = r;
        __syncthreads();
    }
    int gb = ebase + nodes0;
    lb[tid] = sA[tid] - myc;
    cur[tid] = 1;
    __syncthreads();
    if (tid < nnodes) {
        row_start[nodes0 + tid] = gb + lb[tid];
        csr[gb + lb[tid]] = nodes0 + tid;
    }
    __syncthreads();
    for (int e = tid; e < ecnt; e += 256) {
        int v = sbk[e];
        int l = (v >> 17) & 255;
        int src = v & 0x1FFFF;
        int r = atomicAdd(&cur[l], 1);
        csr[gb + lb[l] + r] = src;
    }
}

// Precompute combined att columns: Wc[col][k], col 0-3 = Wa heads (att_src),
// col 4-7 = Wb heads (att_dst), col 8-15 = 0.  Wa[k][h] = sum_c W1[k][h*16+c]*as[h][c].
__global__ __launch_bounds__(128) void k_watt(const float* __restrict__ W1,
                                              const float* __restrict__ att_src,
                                              const float* __restrict__ att_dst,
                                              float* __restrict__ Wc) {
    int k = threadIdx.x;  // 0..127
    #pragma unroll
    for (int h = 0; h < 4; h++) {
        float s = 0.f, d = 0.f;
        #pragma unroll
        for (int c = 0; c < 16; c++) {
            float w = W1[k * 64 + h * 16 + c];
            s += w * att_src[h * 16 + c];
            d += w * att_dst[h * 16 + c];
        }
        Wc[h * 128 + k] = s;
        Wc[(4 + h) * 128 + k] = d;
    }
    #pragma unroll
    for (int col = 8; col < 16; col++) Wc[col * 128 + k] = 0.f;
}

// h1[N,64](fp16) = x[N,128] @ W1[128,64] via MFMA 16x16x32 bf16.
// 5th MFMA computes a_src1/a_dst1 directly from Wc columns (no shuffles).
// C layout: col=lane&15, row=(lane>>4)*4+reg  [m89-verified].
__global__ __launch_bounds__(256) void k_gemm1(const float* __restrict__ x,
                                               const float* __restrict__ W1,
                                               const float* __restrict__ Wc,
                                               __half* __restrict__ h1, float* __restrict__ a_src,
                                               float* __restrict__ a_dst, int N) {
    __shared__ short wt[80 * 136];   // cols 0-63: W1^T; cols 64-79: Wc
    int tid = threadIdx.x;
    for (int i = tid; i < 128 * 64; i += 256) {
        int k = i >> 6, c = i & 63;
        wt[c * 136 + k] = f2bf(W1[i]);
    }
    for (int i = tid; i < 16 * 128; i += 256) {
        int col = i >> 7, k = i & 127;
        wt[(64 + col) * 136 + k] = f2bf(Wc[i]);
    }
    __syncthreads();
    int wave = tid >> 6, lane = tid & 63;
    int m = lane & 15, q = lane >> 4;
    int nbase = blockIdx.x * 64 + wave * 16;
    int anode = nbase + m;
    bool rowok = anode < N;
    const float* xrow = x + (size_t)(rowok ? anode : 0) * 128 + q * 8;

    float4v acc[5];
    #pragma unroll
    for (int ct = 0; ct < 5; ct++)
        #pragma unroll
        for (int r = 0; r < 4; r++) acc[ct][r] = 0.f;

    #pragma unroll
    for (int kc = 0; kc < 4; kc++) {
        float4 u0 = make_float4(0.f, 0.f, 0.f, 0.f), u1 = u0;
        if (rowok) {
            u0 = *(const float4*)(xrow + kc * 32);
            u1 = *(const float4*)(xrow + kc * 32 + 4);
        }
        short8 af;
        af[0] = f2bf(u0.x); af[1] = f2bf(u0.y); af[2] = f2bf(u0.z); af[3] = f2bf(u0.w);
        af[4] = f2bf(u1.x); af[5] = f2bf(u1.y); af[6] = f2bf(u1.z); af[7] = f2bf(u1.w);
        #pragma unroll
        for (int ct = 0; ct < 5; ct++) {
            short8 bf = *(const short8*)&wt[(ct * 16 + m) * 136 + kc * 32 + q * 8];
            acc[ct] = __builtin_amdgcn_mfma_f32_16x16x32_bf16(af, bf, acc[ct], 0, 0, 0);
        }
    }
    // h1 stores: acc[ct][r] = h1[nbase+q*4+r][ct*16+m]
    #pragma unroll
    for (int ct = 0; ct < 4; ct++) {
        #pragma unroll
        for (int r = 0; r < 4; r++) {
            int n = nbase + q * 4 + r;
            if (n < N) h1[(size_t)n * 64 + ct * 16 + m] = __float2half(acc[ct][r]);
        }
    }
    // att outputs: acc[4][r], col m: 0-3 -> a_src head m, 4-7 -> a_dst head m-4
    #pragma unroll
    for (int r = 0; r < 4; r++) {
        int n = nbase + q * 4 + r;
        if (n < N) {
            float v = acc[4][r];
            if (m < 4) a_src[n * 4 + m] = v;
            else if (m < 8) a_dst[n * 4 + (m - 4)] = v;
        }
    }
}

// layer-1 aggregation: one wave per node, no-max softmax, single exp pass (R5/R8)
__global__ __launch_bounds__(256) void k_agg1(const int* __restrict__ row_start,
                                              const int* __restrict__ csr_src,
                                              const float* __restrict__ a_src,
                                              const float* __restrict__ a_dst,
                                              const __half* __restrict__ h1,
                                              const float* __restrict__ bias,
                                              float* __restrict__ out1, int N) {
    __shared__ int   sidx[4][CAP];
    __shared__ float sval[4][CAP * 4];
    int wave = threadIdx.x >> 6, lane = threadIdx.x & 63;
    int node = blockIdx.x * 4 + wave;
    if (node >= N) return;
    int row = row_start[node];
    int deg = row_start[node + 1] - row;
    float4 ad = ((const float4*)a_dst)[node];
    float s0 = 0.f, s1 = 0.f, s2 = 0.f, s3 = 0.f;
    for (int j = lane; j < deg; j += 64) {
        int s = csr_src[row + j];
        float4 as = ((const float4*)a_src)[s];
        float e0 = __expf(LRELU(as.x + ad.x));
        float e1 = __expf(LRELU(as.y + ad.y));
        float e2 = __expf(LRELU(as.z + ad.z));
        float e3 = __expf(LRELU(as.w + ad.w));
        if (j < CAP) {
            sidx[wave][j] = s;
            *(float4*)&sval[wave][j * 4] = make_float4(e0, e1, e2, e3);
        }
        s0 += e0; s1 += e1; s2 += e2; s3 += e3;
    }
    #pragma unroll
    for (int m = 1; m < 64; m <<= 1) {
        s0 += __shfl_xor(s0, m, 64);
        s1 += __shfl_xor(s1, m, 64);
        s2 += __shfl_xor(s2, m, 64);
        s3 += __shfl_xor(s3, m, 64);
    }
    int myh = lane >> 4;
    float ssv = myh == 0 ? s0 : myh == 1 ? s1 : myh == 2 ? s2 : s3;
    float adm = myh == 0 ? ad.x : myh == 1 ? ad.y : myh == 2 ? ad.z : ad.w;
    float iv = 1.f / (ssv + 1e-16f);
    float acc = 0.f, accB = 0.f;
    int dc = deg < CAP ? deg : CAP;
    int j = 0;
    for (; j + 8 <= dc; j += 8) {
        int t0 = sidx[wave][j + 0], t1 = sidx[wave][j + 1];
        int t2 = sidx[wave][j + 2], t3 = sidx[wave][j + 3];
        int t4 = sidx[wave][j + 4], t5 = sidx[wave][j + 5];
        int t6 = sidx[wave][j + 6], t7 = sidx[wave][j + 7];
        float e0 = sval[wave][(j + 0) * 4 + myh], e1 = sval[wave][(j + 1) * 4 + myh];
        float e2 = sval[wave][(j + 2) * 4 + myh], e3 = sval[wave][(j + 3) * 4 + myh];
        float e4 = sval[wave][(j + 4) * 4 + myh], e5 = sval[wave][(j + 5) * 4 + myh];
        float e6 = sval[wave][(j + 6) * 4 + myh], e7 = sval[wave][(j + 7) * 4 + myh];
        float g0 = __half2float(h1[(size_t)t0 * 64 + lane]);
        float g1 = __half2float(h1[(size_t)t1 * 64 + lane]);
        float g2 = __half2float(h1[(size_t)t2 * 64 + lane]);
        float g3 = __half2float(h1[(size_t)t3 * 64 + lane]);
        float g4 = __half2float(h1[(size_t)t4 * 64 + lane]);
        float g5 = __half2float(h1[(size_t)t5 * 64 + lane]);
        float g6 = __half2float(h1[(size_t)t6 * 64 + lane]);
        float g7 = __half2float(h1[(size_t)t7 * 64 + lane]);
        acc  += e0 * g0 + e2 * g2 + e4 * g4 + e6 * g6;
        accB += e1 * g1 + e3 * g3 + e5 * g5 + e7 * g7;
    }
    for (; j + 4 <= dc; j += 4) {
        int t0 = sidx[wave][j + 0], t1 = sidx[wave][j + 1];
        int t2 = sidx[wave][j + 2], t3 = sidx[wave][j + 3];
        float e0 = sval[wave][(j + 0) * 4 + myh], e1 = sval[wave][(j + 1) * 4 + myh];
        float e2 = sval[wave][(j + 2) * 4 + myh], e3 = sval[wave][(j + 3) * 4 + myh];
        float g0 = __half2float(h1[(size_t)t0 * 64 + lane]);
        float g1 = __half2float(h1[(size_t)t1 * 64 + lane]);
        float g2 = __half2float(h1[(size_t)t2 * 64 + lane]);
        float g3 = __half2float(h1[(size_t)t3 * 64 + lane]);
        acc  += e0 * g0 + e2 * g2;
        accB += e1 * g1 + e3 * g3;
    }
    for (; j < dc; j++)
        acc += sval[wave][j * 4 + myh] * __half2float(h1[(size_t)sidx[wave][j] * 64 + lane]);
    for (; j < deg; j++) {
        int s = csr_src[row + j];
        float e = __expf(LRELU(a_src[s * 4 + myh] + adm));
        acc += e * __half2float(h1[(size_t)s * 64 + lane]);
    }
    acc = (acc + accB) * iv;
    float o = acc + bias[lane];
    o = (o > 0.f) ? o : (__expf(o) - 1.f);  // ELU
    out1[(size_t)node * 64 + lane] = o;
}

// h2[N,16] = out1[N,64] @ W2[64,16]; fused att2 dots (R5)
__global__ __launch_bounds__(256) void k_gemm2(const float* __restrict__ out1,
                                               const float* __restrict__ W2,
                                               const float* __restrict__ att_src,
                                               const float* __restrict__ att_dst,
                                               float* __restrict__ h2, float* __restrict__ a_src,
                                               float* __restrict__ a_dst, int N) {
    __shared__ float ws[64 * 16];
    __shared__ float xs[16 * 65];
    int tid = threadIdx.x;
    for (int i = tid; i < 64 * 16; i += 256) ws[i] = W2[i];
    int n0 = blockIdx.x * 16;
    for (int i = tid; i < 16 * 64; i += 256) {
        int r = i >> 6, c = i & 63;
        int n = n0 + r;
        xs[r * 65 + c] = (n < N) ? out1[(size_t)n * 64 + c] : 0.f;
    }
    __syncthreads();
    int nl = tid >> 4, c = tid & 15;
    int n = n0 + nl;
    float acc = 0.f;
    #pragma unroll
    for (int k = 0; k < 64; k++) acc += xs[nl * 65 + k] * ws[k * 16 + c];
    float asv = acc * att_src[c];
    float adv = acc * att_dst[c];
    #pragma unroll
    for (int m = 1; m < 16; m <<= 1) {
        asv += __shfl_xor(asv, m, 64);
        adv += __shfl_xor(adv, m, 64);
    }
    if (n < N) {
        h2[(size_t)n * 16 + c] = acc;
        if (c == 0) { a_src[n] = asv; a_dst[n] = adv; }
    }
}

// layer-2 aggregation + bias + log_softmax; 2 nodes per wave (8 per block)
#define CAP2 64
__global__ __launch_bounds__(256) void k_agg2(const int* __restrict__ row_start,
                                              const int* __restrict__ csr_src,
                                              const float* __restrict__ a_src,
                                              const float* __restrict__ a_dst,
                                              const float* __restrict__ h2,
                                              const float* __restrict__ bias,
                                              float* __restrict__ out, int N) {
    __shared__ int   sidx[4][2][CAP2];
    __shared__ float sval[4][2][CAP2];
    int wave = threadIdx.x >> 6, lane = threadIdx.x & 63;
    int half = lane >> 5, l32 = lane & 31;
    int node = blockIdx.x * 8 + wave * 2 + half;
    if (node >= N) return;
    int row = row_start[node];
    int deg = row_start[node + 1] - row;
    float ad = a_dst[node];
    float sh = 0.f;
    for (int j = l32; j < deg; j += 32) {
        int s = csr_src[row + j];
        float e = __expf(LRELU(a_src[s] + ad));
        if (j < CAP2) { sidx[wave][half][j] = s; sval[wave][half][j] = e; }
        sh += e;
    }
    #pragma unroll
    for (int m = 1; m < 32; m <<= 1) sh += __shfl_xor(sh, m, 64);
    float iv = 1.f / (sh + 1e-16f);
    int c = l32 & 15, sub = l32 >> 4;      // 2 subgroups of 16 ch per node
    float acc = 0.f, acc2 = 0.f;
    int dc = deg < CAP2 ? deg : CAP2;
    int j = sub;
    for (; j + 2 < dc; j += 4) {
        int t0 = sidx[wave][half][j], t1 = sidx[wave][half][j + 2];
        float e0 = sval[wave][half][j], e1 = sval[wave][half][j + 2];
        float g0 = h2[(size_t)t0 * 16 + c], g1 = h2[(size_t)t1 * 16 + c];
        acc += e0 * g0; acc2 += e1 * g1;
    }
    for (; j < deg; j += 2) {
        int s; float e;
        if (j < dc) { s = sidx[wave][half][j]; e = sval[wave][half][j]; }
        else { s = csr_src[row + j]; e = __expf(LRELU(a_src[s] + ad)); }
        acc += e * h2[(size_t)s * 16 + c];
    }
    acc += acc2;
    acc += __shfl_xor(acc, 16, 64);        // combine the 2 subgroups (same half)
    float val = acc * iv + bias[c];
    float mx = val;
    #pragma unroll
    for (int m = 1; m < 16; m <<= 1) mx = fmaxf(mx, __shfl_xor(mx, m, 64));
    float se = __expf(val - mx);
    #pragma unroll
    for (int m = 1; m < 16; m <<= 1) se += __shfl_xor(se, m, 64);
    float o = val - mx - __logf(se);
    if (sub == 0) out[(size_t)node * 16 + c] = o;
}

extern "C" void kernel_launch(void* const* d_in, const int* in_sizes, int n_in,
                              void* d_out, int out_size, void* d_ws, size_t ws_size,
                              hipStream_t stream) {
    const float* x        = (const float*)d_in[0];
    const int*   ei       = (const int*)d_in[1];
    const float* W1       = (const float*)d_in[2];
    const float* att_src1 = (const float*)d_in[3];
    const float* att_dst1 = (const float*)d_in[4];
    const float* bias1    = (const float*)d_in[5];
    const float* W2       = (const float*)d_in[6];
    const float* att_src2 = (const float*)d_in[7];
    const float* att_dst2 = (const float*)d_in[8];
    const float* bias2    = (const float*)d_in[9];
    float* out = (float*)d_out;

    const int N = in_sizes[0] / 128;
    const int E = in_sizes[1] / 2;
    const int NBK = (N + 255) >> BSH;

    char* p = (char*)d_ws;
    auto alloc = [&](size_t bytes) -> void* {
        void* r = (void*)p;
        p += (bytes + 255) & ~(size_t)255;
        return r;
    };
    __half* h1     = (__half*)alloc((size_t)N * 64 * 2);
    float* out1    = (float*)alloc((size_t)N * 64 * 4);
    float* h2      = (float*)alloc((size_t)N * 16 * 4);
    float* a_src1  = (float*)alloc((size_t)N * 4 * 4);
    float* a_dst1  = (float*)alloc((size_t)N * 4 * 4);
    float* a_src2  = (float*)alloc((size_t)N * 4);
    float* a_dst2  = (float*)alloc((size_t)N * 4);
    float* Wc      = (float*)alloc(16 * 128 * 4);
    int*   row_st  = (int*)alloc((size_t)(N + 1) * 4);
    int*   csr     = (int*)alloc((size_t)(E + N) * 4);
    int*   stage   = (int*)alloc((size_t)NBK * BCAP * 4);
    int*   cursor  = (int*)alloc((size_t)NBK * 4);
    int*   gbase   = (int*)alloc((size_t)(NBK + 1) * 4);
    (void)ws_size; (void)n_in; (void)out_size;

    hipMemsetAsync(cursor, 0, (size_t)NBK * 4, stream);
    k_watt<<<1, 128, 0, stream>>>(W1, att_src1, att_dst1, Wc);
    k_scatter<<<(E + CHK - 1) / CHK, 256, 0, stream>>>(ei, cursor, stage, E, NBK);
    k_bucket_scan<<<1, 256, 0, stream>>>(cursor, gbase, row_st, NBK, E, N);
    k_build<<<NBK, 256, 0, stream>>>(stage, gbase, row_st, csr, N);
    k_gemm1<<<(N + 63) / 64, 256, 0, stream>>>(x, W1, Wc, h1, a_src1, a_dst1, N);
    k_agg1<<<(N + 3) / 4, 256, 0, stream>>>(row_st, csr, a_src1, a_dst1, h1, bias1, out1, N);
    k_gemm2<<<(N + 15) / 16, 256, 0, stream>>>(out1, W2, att_src2, att_dst2, h2, a_src2, a_dst2, N);
    k_agg2<<<(N + 7) / 8, 256, 0, stream>>>(row_st, csr, a_src2, a_dst2, h2, bias2, out, N);
}

// Round 10
// 263.229 us; speedup vs baseline: 1.1539x; 1.0712x over previous
//
#include <hip/hip_runtime.h>
#include <hip/hip_fp16.h>
#include <hip/hip_bf16.h>
#include <math.h>

// GAT 2-layer forward, MI355X. FP32 in/out, int32 edge_index.
// R10: agg1 2-nodes-per-wave (two independent gather latency chains/wave,
// half-wave = 32 lanes x half2 channels); h2 in fp16 (halves agg2 gather
// lines, fits per-XCD L2). gemm1/CSR/agg2-structure from R9.

#define LRELU(v) ((v) > 0.f ? (v) : 0.2f * (v))
#define BSH 8            // 256 nodes per bucket
#define BCAP 5120        // staged capacity per bucket
#define CHK 2048         // edges per k_scatter block
#define CAP1 64          // agg1 LDS edge cache per node (2 nodes/wave)
#define CAP2 64          // agg2 LDS edge cache per node

typedef __attribute__((ext_vector_type(8))) short short8;
typedef __attribute__((ext_vector_type(4))) float float4v;

static __device__ __forceinline__ short f2bf(float f) {
    __hip_bfloat16 b = __float2bfloat16(f);
    return *reinterpret_cast<short*>(&b);
}

// Pass 1: bin edges by dst bucket, stage reordered in LDS, flush dense runs.
__global__ __launch_bounds__(256) void k_scatter(const int* __restrict__ ei, int* __restrict__ cursor,
                                                 int* __restrict__ stage, int E, int NBK) {
    __shared__ int sval[CHK];
    __shared__ int gaddr[CHK];
    __shared__ int sdst[CHK];
    __shared__ int hist[512];
    __shared__ int lbase[512];
    __shared__ int cnt2[512];
    __shared__ int gdelta[512];
    __shared__ int sA[512];
    int tid = threadIdx.x;
    int e0 = blockIdx.x * CHK;
    int nedge = E - e0; if (nedge > CHK) nedge = CHK;

    for (int i = tid; i < 512; i += 256) { hist[i] = 0; cnt2[i] = 0; }
    __syncthreads();
    for (int j = tid; j < nedge; j += 256) {
        int d = ei[E + e0 + j];
        sdst[j] = d;
        atomicAdd(&hist[d >> BSH], 1);
    }
    __syncthreads();
    sA[tid] = hist[tid]; sA[tid + 256] = hist[tid + 256];
    __syncthreads();
    for (int off = 1; off < 512; off <<= 1) {
        int r0 = sA[tid] + ((tid >= off) ? sA[tid - off] : 0);
        int r1 = sA[tid + 256] + ((tid + 256 >= off) ? sA[tid + 256 - off] : 0);
        __syncthreads();
        sA[tid] = r0; sA[tid + 256] = r1;
        __syncthreads();
    }
    for (int i = tid; i < 512; i += 256) lbase[i] = sA[i] - hist[i];
    __syncthreads();
    for (int b = tid; b < NBK; b += 256) {
        int c = hist[b];
        if (c > 0) {
            int rel = atomicAdd(&cursor[b], c);
            gdelta[b] = b * BCAP + rel - lbase[b];
        }
    }
    __syncthreads();
    for (int j = tid; j < nedge; j += 256) {
        int s = ei[e0 + j];
        int d = sdst[j];
        int b = d >> BSH;
        int r = atomicAdd(&cnt2[b], 1);
        int slot = lbase[b] + r;
        sval[slot]  = s | ((d & ((1 << BSH) - 1)) << 17);
        gaddr[slot] = gdelta[b] + slot;
    }
    __syncthreads();
    for (int s = tid; s < nedge; s += 256) stage[gaddr[s]] = sval[s];
}

// exclusive scan of bucket counts -> gbase[NBK+1]; row_start[N] tail
__global__ __launch_bounds__(256) void k_bucket_scan(const int* __restrict__ cursor,
                                                     int* __restrict__ gbase,
                                                     int* __restrict__ row_start,
                                                     int NBK, int E, int N) {
    __shared__ int sA[512];
    __shared__ int cnt[512];
    int tid = threadIdx.x;
    for (int i = tid; i < 512; i += 256)
        cnt[i] = (i < NBK) ? cursor[i] : 0;
    __syncthreads();
    sA[tid] = cnt[tid]; sA[tid + 256] = cnt[tid + 256];
    __syncthreads();
    for (int off = 1; off < 512; off <<= 1) {
        int r0 = sA[tid] + ((tid >= off) ? sA[tid - off] : 0);
        int r1 = sA[tid + 256] + ((tid + 256 >= off) ? sA[tid + 256 - off] : 0);
        __syncthreads();
        sA[tid] = r0; sA[tid + 256] = r1;
        __syncthreads();
    }
    for (int i = tid; i < 512; i += 256)
        if (i < NBK) gbase[i] = sA[i] - cnt[i];
    if (tid == 0) { gbase[NBK] = E; row_start[N] = E + N; }
}

// Pass 2: per-bucket fine CSR build (L2-hot window -> dense writeback)
__global__ __launch_bounds__(256) void k_build(const int* __restrict__ stage,
                                               const int* __restrict__ gbase,
                                               int* __restrict__ row_start,
                                               int* __restrict__ csr, int N) {
    __shared__ int cnt[256];
    __shared__ int lb[256];
    __shared__ int cur[256];
    __shared__ int sA[256];
    int b = blockIdx.x, tid = threadIdx.x;
    int nodes0 = b << BSH;
    int nnodes = N - nodes0; if (nnodes > 256) nnodes = 256;
    int ebase = gbase[b];
    int ecnt = gbase[b + 1] - ebase;
    const int* sbk = stage + b * BCAP;
    cnt[tid] = (tid < nnodes) ? 1 : 0;  // self loop
    __syncthreads();
    for (int e = tid; e < ecnt; e += 256) {
        int l = (sbk[e] >> 17) & 255;
        atomicAdd(&cnt[l], 1);
    }
    __syncthreads();
    int myc = cnt[tid];
    sA[tid] = myc;
    __syncthreads();
    for (int off = 1; off < 256; off <<= 1) {
        int r = sA[tid] + ((tid >= off) ? sA[tid - off] : 0);
        __syncthreads();
        sA[tid] = r;
        __syncthreads();
    }
    int gb = ebase + nodes0;
    lb[tid] = sA[tid] - myc;
    cur[tid] = 1;
    __syncthreads();
    if (tid < nnodes) {
        row_start[nodes0 + tid] = gb + lb[tid];
        csr[gb + lb[tid]] = nodes0 + tid;
    }
    __syncthreads();
    for (int e = tid; e < ecnt; e += 256) {
        int v = sbk[e];
        int l = (v >> 17) & 255;
        int src = v & 0x1FFFF;
        int r = atomicAdd(&cur[l], 1);
        csr[gb + lb[l] + r] = src;
    }
}

// Precompute combined att columns: Wc[col][k], col 0-3 = Wa heads (att_src),
// col 4-7 = Wb heads (att_dst), col 8-15 = 0.
__global__ __launch_bounds__(128) void k_watt(const float* __restrict__ W1,
                                              const float* __restrict__ att_src,
                                              const float* __restrict__ att_dst,
                                              float* __restrict__ Wc) {
    int k = threadIdx.x;  // 0..127
    #pragma unroll
    for (int h = 0; h < 4; h++) {
        float s = 0.f, d = 0.f;
        #pragma unroll
        for (int c = 0; c < 16; c++) {
            float w = W1[k * 64 + h * 16 + c];
            s += w * att_src[h * 16 + c];
            d += w * att_dst[h * 16 + c];
        }
        Wc[h * 128 + k] = s;
        Wc[(4 + h) * 128 + k] = d;
    }
    #pragma unroll
    for (int col = 8; col < 16; col++) Wc[col * 128 + k] = 0.f;
}

// h1[N,64](fp16) = x[N,128] @ W1[128,64] via MFMA 16x16x32 bf16 (R9).
__global__ __launch_bounds__(256) void k_gemm1(const float* __restrict__ x,
                                               const float* __restrict__ W1,
                                               const float* __restrict__ Wc,
                                               __half* __restrict__ h1, float* __restrict__ a_src,
                                               float* __restrict__ a_dst, int N) {
    __shared__ short wt[80 * 136];   // cols 0-63: W1^T; cols 64-79: Wc
    int tid = threadIdx.x;
    for (int i = tid; i < 128 * 64; i += 256) {
        int k = i >> 6, c = i & 63;
        wt[c * 136 + k] = f2bf(W1[i]);
    }
    for (int i = tid; i < 16 * 128; i += 256) {
        int col = i >> 7, k = i & 127;
        wt[(64 + col) * 136 + k] = f2bf(Wc[i]);
    }
    __syncthreads();
    int wave = tid >> 6, lane = tid & 63;
    int m = lane & 15, q = lane >> 4;
    int nbase = blockIdx.x * 64 + wave * 16;
    int anode = nbase + m;
    bool rowok = anode < N;
    const float* xrow = x + (size_t)(rowok ? anode : 0) * 128 + q * 8;

    float4v acc[5];
    #pragma unroll
    for (int ct = 0; ct < 5; ct++)
        #pragma unroll
        for (int r = 0; r < 4; r++) acc[ct][r] = 0.f;

    #pragma unroll
    for (int kc = 0; kc < 4; kc++) {
        float4 u0 = make_float4(0.f, 0.f, 0.f, 0.f), u1 = u0;
        if (rowok) {
            u0 = *(const float4*)(xrow + kc * 32);
            u1 = *(const float4*)(xrow + kc * 32 + 4);
        }
        short8 af;
        af[0] = f2bf(u0.x); af[1] = f2bf(u0.y); af[2] = f2bf(u0.z); af[3] = f2bf(u0.w);
        af[4] = f2bf(u1.x); af[5] = f2bf(u1.y); af[6] = f2bf(u1.z); af[7] = f2bf(u1.w);
        #pragma unroll
        for (int ct = 0; ct < 5; ct++) {
            short8 bf = *(const short8*)&wt[(ct * 16 + m) * 136 + kc * 32 + q * 8];
            acc[ct] = __builtin_amdgcn_mfma_f32_16x16x32_bf16(af, bf, acc[ct], 0, 0, 0);
        }
    }
    #pragma unroll
    for (int ct = 0; ct < 4; ct++) {
        #pragma unroll
        for (int r = 0; r < 4; r++) {
            int n = nbase + q * 4 + r;
            if (n < N) h1[(size_t)n * 64 + ct * 16 + m] = __float2half(acc[ct][r]);
        }
    }
    #pragma unroll
    for (int r = 0; r < 4; r++) {
        int n = nbase + q * 4 + r;
        if (n < N) {
            float v = acc[4][r];
            if (m < 4) a_src[n * 4 + m] = v;
            else if (m < 8) a_dst[n * 4 + (m - 4)] = v;
        }
    }
}

// layer-1 aggregation: 2 nodes per wave (32 lanes x half2 channels each),
// two independent gather latency chains per wave.
__global__ __launch_bounds__(256) void k_agg1(const int* __restrict__ row_start,
                                              const int* __restrict__ csr_src,
                                              const float* __restrict__ a_src,
                                              const float* __restrict__ a_dst,
                                              const __half* __restrict__ h1,
                                              const float* __restrict__ bias,
                                              float* __restrict__ out1, int N) {
    __shared__ int   sidx[4][2][CAP1];
    __shared__ float sval[4][2][CAP1 * 4];
    int wave = threadIdx.x >> 6, lane = threadIdx.x & 63;
    int half = lane >> 5, l32 = lane & 31;
    int node = blockIdx.x * 8 + wave * 2 + half;
    if (node >= N) return;
    int row = row_start[node];
    int deg = row_start[node + 1] - row;
    float4 ad = ((const float4*)a_dst)[node];
    // phase 1: exp + sum over this half's node (32 lanes)
    float s0 = 0.f, s1 = 0.f, s2 = 0.f, s3 = 0.f;
    for (int j = l32; j < deg; j += 32) {
        int s = csr_src[row + j];
        float4 as = ((const float4*)a_src)[s];
        float e0 = __expf(LRELU(as.x + ad.x));
        float e1 = __expf(LRELU(as.y + ad.y));
        float e2 = __expf(LRELU(as.z + ad.z));
        float e3 = __expf(LRELU(as.w + ad.w));
        if (j < CAP1) {
            sidx[wave][half][j] = s;
            *(float4*)&sval[wave][half][j * 4] = make_float4(e0, e1, e2, e3);
        }
        s0 += e0; s1 += e1; s2 += e2; s3 += e3;
    }
    #pragma unroll
    for (int m = 1; m < 32; m <<= 1) {   // within-half butterflies
        s0 += __shfl_xor(s0, m, 64);
        s1 += __shfl_xor(s1, m, 64);
        s2 += __shfl_xor(s2, m, 64);
        s3 += __shfl_xor(s3, m, 64);
    }
    // phase 2: lane = channel pair (2*l32, 2*l32+1); head = l32>>3
    int myh = l32 >> 3;
    float ssv = myh == 0 ? s0 : myh == 1 ? s1 : myh == 2 ? s2 : s3;
    float adm = myh == 0 ? ad.x : myh == 1 ? ad.y : myh == 2 ? ad.z : ad.w;
    float iv = 1.f / (ssv + 1e-16f);
    float ax = 0.f, ay = 0.f, bx = 0.f, by = 0.f;
    int dc = deg < CAP1 ? deg : CAP1;
    int j = 0;
    for (; j + 8 <= dc; j += 8) {
        int t0 = sidx[wave][half][j + 0], t1 = sidx[wave][half][j + 1];
        int t2 = sidx[wave][half][j + 2], t3 = sidx[wave][half][j + 3];
        int t4 = sidx[wave][half][j + 4], t5 = sidx[wave][half][j + 5];
        int t6 = sidx[wave][half][j + 6], t7 = sidx[wave][half][j + 7];
        float e0 = sval[wave][half][(j + 0) * 4 + myh], e1 = sval[wave][half][(j + 1) * 4 + myh];
        float e2 = sval[wave][half][(j + 2) * 4 + myh], e3 = sval[wave][half][(j + 3) * 4 + myh];
        float e4 = sval[wave][half][(j + 4) * 4 + myh], e5 = sval[wave][half][(j + 5) * 4 + myh];
        float e6 = sval[wave][half][(j + 6) * 4 + myh], e7 = sval[wave][half][(j + 7) * 4 + myh];
        float2 g0 = __half22float2(*(const __half2*)&h1[(size_t)t0 * 64 + l32 * 2]);
        float2 g1 = __half22float2(*(const __half2*)&h1[(size_t)t1 * 64 + l32 * 2]);
        float2 g2 = __half22float2(*(const __half2*)&h1[(size_t)t2 * 64 + l32 * 2]);
        float2 g3 = __half22float2(*(const __half2*)&h1[(size_t)t3 * 64 + l32 * 2]);
        float2 g4 = __half22float2(*(const __half2*)&h1[(size_t)t4 * 64 + l32 * 2]);
        float2 g5 = __half22float2(*(const __half2*)&h1[(size_t)t5 * 64 + l32 * 2]);
        float2 g6 = __half22float2(*(const __half2*)&h1[(size_t)t6 * 64 + l32 * 2]);
        float2 g7 = __half22float2(*(const __half2*)&h1[(size_t)t7 * 64 + l32 * 2]);
        ax += e0 * g0.x + e2 * g2.x + e4 * g4.x + e6 * g6.x;
        ay += e0 * g0.y + e2 * g2.y + e4 * g4.y + e6 * g6.y;
        bx += e1 * g1.x + e3 * g3.x + e5 * g5.x + e7 * g7.x;
        by += e1 * g1.y + e3 * g3.y + e5 * g5.y + e7 * g7.y;
    }
    for (; j < dc; j++) {
        int t = sidx[wave][half][j];
        float e = sval[wave][half][j * 4 + myh];
        float2 g = __half22float2(*(const __half2*)&h1[(size_t)t * 64 + l32 * 2]);
        ax += e * g.x; ay += e * g.y;
    }
    for (; j < deg; j++) {   // deg > CAP1 fallback
        int s = csr_src[row + j];
        float e = __expf(LRELU(a_src[s * 4 + myh] + adm));
        float2 g = __half22float2(*(const __half2*)&h1[(size_t)s * 64 + l32 * 2]);
        ax += e * g.x; ay += e * g.y;
    }
    ax += bx; ay += by;
    float2 bb = ((const float2*)bias)[l32];
    float ox = ax * iv + bb.x;
    float oy = ay * iv + bb.y;
    ox = (ox > 0.f) ? ox : (__expf(ox) - 1.f);  // ELU
    oy = (oy > 0.f) ? oy : (__expf(oy) - 1.f);
    ((float2*)out1)[(size_t)node * 32 + l32] = make_float2(ox, oy);
}

// h2[N,16](fp16) = out1[N,64] @ W2[64,16]; fused att2 dots
__global__ __launch_bounds__(256) void k_gemm2(const float* __restrict__ out1,
                                               const float* __restrict__ W2,
                                               const float* __restrict__ att_src,
                                               const float* __restrict__ att_dst,
                                               __half* __restrict__ h2, float* __restrict__ a_src,
                                               float* __restrict__ a_dst, int N) {
    __shared__ float ws[64 * 16];
    __shared__ float xs[16 * 65];
    int tid = threadIdx.x;
    for (int i = tid; i < 64 * 16; i += 256) ws[i] = W2[i];
    int n0 = blockIdx.x * 16;
    for (int i = tid; i < 16 * 64; i += 256) {
        int r = i >> 6, c = i & 63;
        int n = n0 + r;
        xs[r * 65 + c] = (n < N) ? out1[(size_t)n * 64 + c] : 0.f;
    }
    __syncthreads();
    int nl = tid >> 4, c = tid & 15;
    int n = n0 + nl;
    float acc = 0.f;
    #pragma unroll
    for (int k = 0; k < 64; k++) acc += xs[nl * 65 + k] * ws[k * 16 + c];
    float asv = acc * att_src[c];
    float adv = acc * att_dst[c];
    #pragma unroll
    for (int m = 1; m < 16; m <<= 1) {
        asv += __shfl_xor(asv, m, 64);
        adv += __shfl_xor(adv, m, 64);
    }
    if (n < N) {
        h2[(size_t)n * 16 + c] = __float2half(acc);
        if (c == 0) { a_src[n] = asv; a_dst[n] = adv; }
    }
}

// layer-2 aggregation + bias + log_softmax; 2 nodes/wave, fp16 h2 gathers
__global__ __launch_bounds__(256) void k_agg2(const int* __restrict__ row_start,
                                              const int* __restrict__ csr_src,
                                              const float* __restrict__ a_src,
                                              const float* __restrict__ a_dst,
                                              const __half* __restrict__ h2,
                                              const float* __restrict__ bias,
                                              float* __restrict__ out, int N) {
    __shared__ int   sidx[4][2][CAP2];
    __shared__ float sval[4][2][CAP2];
    int wave = threadIdx.x >> 6, lane = threadIdx.x & 63;
    int half = lane >> 5, l32 = lane & 31;
    int node = blockIdx.x * 8 + wave * 2 + half;
    if (node >= N) return;
    int row = row_start[node];
    int deg = row_start[node + 1] - row;
    float ad = a_dst[node];
    float sh = 0.f;
    for (int j = l32; j < deg; j += 32) {
        int s = csr_src[row + j];
        float e = __expf(LRELU(a_src[s] + ad));
        if (j < CAP2) { sidx[wave][half][j] = s; sval[wave][half][j] = e; }
        sh += e;
    }
    #pragma unroll
    for (int m = 1; m < 32; m <<= 1) sh += __shfl_xor(sh, m, 64);
    float iv = 1.f / (sh + 1e-16f);
    // gather: lane = cg(0..7 -> channel pair) x eg(0..3 edge slot)
    int cg = l32 & 7, eg = l32 >> 3;
    float ax = 0.f, ay = 0.f, bx = 0.f, by = 0.f;
    int dc = deg < CAP2 ? deg : CAP2;
    int j = eg;
    for (; j + 4 < dc; j += 8) {
        int t0 = sidx[wave][half][j], t1 = sidx[wave][half][j + 4];
        float e0 = sval[wave][half][j], e1 = sval[wave][half][j + 4];
        float2 g0 = __half22float2(*(const __half2*)&h2[(size_t)t0 * 16 + cg * 2]);
        float2 g1 = __half22float2(*(const __half2*)&h2[(size_t)t1 * 16 + cg * 2]);
        ax += e0 * g0.x; ay += e0 * g0.y;
        bx += e1 * g1.x; by += e1 * g1.y;
    }
    for (; j < deg; j += 4) {
        int s; float e;
        if (j < dc) { s = sidx[wave][half][j]; e = sval[wave][half][j]; }
        else { s = csr_src[row + j]; e = __expf(LRELU(a_src[s] + ad)); }
        float2 g = __half22float2(*(const __half2*)&h2[(size_t)s * 16 + cg * 2]);
        ax += e * g.x; ay += e * g.y;
    }
    ax += bx; ay += by;
    #pragma unroll
    for (int m = 8; m < 32; m <<= 1) {   // combine 4 edge subgroups (within half)
        ax += __shfl_xor(ax, m, 64);
        ay += __shfl_xor(ay, m, 64);
    }
    float2 bb = ((const float2*)bias)[cg];
    float vx = ax * iv + bb.x;
    float vy = ay * iv + bb.y;
    // log_softmax over 16 channels (pairs across lanes cg=0..7)
    float mx = fmaxf(vx, vy);
    #pragma unroll
    for (int m = 1; m < 8; m <<= 1) mx = fmaxf(mx, __shfl_xor(mx, m, 64));
    float se = __expf(vx - mx) + __expf(vy - mx);
    #pragma unroll
    for (int m = 1; m < 8; m <<= 1) se += __shfl_xor(se, m, 64);
    float ls = mx + __logf(se);
    if (eg == 0)
        ((float2*)out)[(size_t)node * 8 + cg] = make_float2(vx - ls, vy - ls);
}

extern "C" void kernel_launch(void* const* d_in, const int* in_sizes, int n_in,
                              void* d_out, int out_size, void* d_ws, size_t ws_size,
                              hipStream_t stream) {
    const float* x        = (const float*)d_in[0];
    const int*   ei       = (const int*)d_in[1];
    const float* W1       = (const float*)d_in[2];
    const float* att_src1 = (const float*)d_in[3];
    const float* att_dst1 = (const float*)d_in[4];
    const float* bias1    = (const float*)d_in[5];
    const float* W2       = (const float*)d_in[6];
    const float* att_src2 = (const float*)d_in[7];
    const float* att_dst2 = (const float*)d_in[8];
    const float* bias2    = (const float*)d_in[9];
    float* out = (float*)d_out;

    const int N = in_sizes[0] / 128;
    const int E = in_sizes[1] / 2;
    const int NBK = (N + 255) >> BSH;

    char* p = (char*)d_ws;
    auto alloc = [&](size_t bytes) -> void* {
        void* r = (void*)p;
        p += (bytes + 255) & ~(size_t)255;
        return r;
    };
    __half* h1     = (__half*)alloc((size_t)N * 64 * 2);
    float* out1    = (float*)alloc((size_t)N * 64 * 4);
    __half* h2     = (__half*)alloc((size_t)N * 16 * 2);
    float* a_src1  = (float*)alloc((size_t)N * 4 * 4);
    float* a_dst1  = (float*)alloc((size_t)N * 4 * 4);
    float* a_src2  = (float*)alloc((size_t)N * 4);
    float* a_dst2  = (float*)alloc((size_t)N * 4);
    float* Wc      = (float*)alloc(16 * 128 * 4);
    int*   row_st  = (int*)alloc((size_t)(N + 1) * 4);
    int*   csr     = (int*)alloc((size_t)(E + N) * 4);
    int*   stage   = (int*)alloc((size_t)NBK * BCAP * 4);
    int*   cursor  = (int*)alloc((size_t)NBK * 4);
    int*   gbase   = (int*)alloc((size_t)(NBK + 1) * 4);
    (void)ws_size; (void)n_in; (void)out_size;

    hipMemsetAsync(cursor, 0, (size_t)NBK * 4, stream);
    k_watt<<<1, 128, 0, stream>>>(W1, att_src1, att_dst1, Wc);
    k_scatter<<<(E + CHK - 1) / CHK, 256, 0, stream>>>(ei, cursor, stage, E, NBK);
    k_bucket_scan<<<1, 256, 0, stream>>>(cursor, gbase, row_st, NBK, E, N);
    k_build<<<NBK, 256, 0, stream>>>(stage, gbase, row_st, csr, N);
    k_gemm1<<<(N + 63) / 64, 256, 0, stream>>>(x, W1, Wc, h1, a_src1, a_dst1, N);
    k_agg1<<<(N + 7) / 8, 256, 0, stream>>>(row_st, csr, a_src1, a_dst1, h1, bias1, out1, N);
    k_gemm2<<<(N + 15) / 16, 256, 0, stream>>>(out1, W2, att_src2, att_dst2, h2, a_src2, a_dst2, N);
    k_agg2<<<(N + 7) / 8, 256, 0, stream>>>(row_st, csr, a_src2, a_dst2, h2, bias2, out, N);
}

// Round 11
// 258.050 us; speedup vs baseline: 1.1771x; 1.0201x over previous
//
#include <hip/hip_runtime.h>
#include <hip/hip_fp16.h>
#include <hip/hip_bf16.h>
#include <math.h>

// GAT 2-layer forward, MI355X. FP32 in/out, int32 edge_index.
// R11: agg1/agg2 4-nodes-per-wave (4 independent gather latency chains per
// wave; 16 lanes x 4ch via 8B fp16x4 loads); k_watt folded into bucket_scan.

#define LRELU(v) ((v) > 0.f ? (v) : 0.2f * (v))
#define BSH 8            // 256 nodes per bucket
#define BCAP 5120        // staged capacity per bucket
#define CHK 2048         // edges per k_scatter block
#define CAP1 64          // agg1 LDS edge cache per node
#define CAP2 64          // agg2 LDS edge cache per node

typedef __attribute__((ext_vector_type(8))) short short8;
typedef __attribute__((ext_vector_type(4))) float float4v;

static __device__ __forceinline__ short f2bf(float f) {
    __hip_bfloat16 b = __float2bfloat16(f);
    return *reinterpret_cast<short*>(&b);
}

// Pass 1: bin edges by dst bucket, stage reordered in LDS, flush dense runs.
__global__ __launch_bounds__(256) void k_scatter(const int* __restrict__ ei, int* __restrict__ cursor,
                                                 int* __restrict__ stage, int E, int NBK) {
    __shared__ int sval[CHK];
    __shared__ int gaddr[CHK];
    __shared__ int sdst[CHK];
    __shared__ int hist[512];
    __shared__ int lbase[512];
    __shared__ int cnt2[512];
    __shared__ int gdelta[512];
    __shared__ int sA[512];
    int tid = threadIdx.x;
    int e0 = blockIdx.x * CHK;
    int nedge = E - e0; if (nedge > CHK) nedge = CHK;

    for (int i = tid; i < 512; i += 256) { hist[i] = 0; cnt2[i] = 0; }
    __syncthreads();
    for (int j = tid; j < nedge; j += 256) {
        int d = ei[E + e0 + j];
        sdst[j] = d;
        atomicAdd(&hist[d >> BSH], 1);
    }
    __syncthreads();
    sA[tid] = hist[tid]; sA[tid + 256] = hist[tid + 256];
    __syncthreads();
    for (int off = 1; off < 512; off <<= 1) {
        int r0 = sA[tid] + ((tid >= off) ? sA[tid - off] : 0);
        int r1 = sA[tid + 256] + ((tid + 256 >= off) ? sA[tid + 256 - off] : 0);
        __syncthreads();
        sA[tid] = r0; sA[tid + 256] = r1;
        __syncthreads();
    }
    for (int i = tid; i < 512; i += 256) lbase[i] = sA[i] - hist[i];
    __syncthreads();
    for (int b = tid; b < NBK; b += 256) {
        int c = hist[b];
        if (c > 0) {
            int rel = atomicAdd(&cursor[b], c);
            gdelta[b] = b * BCAP + rel - lbase[b];
        }
    }
    __syncthreads();
    for (int j = tid; j < nedge; j += 256) {
        int s = ei[e0 + j];
        int d = sdst[j];
        int b = d >> BSH;
        int r = atomicAdd(&cnt2[b], 1);
        int slot = lbase[b] + r;
        sval[slot]  = s | ((d & ((1 << BSH) - 1)) << 17);
        gaddr[slot] = gdelta[b] + slot;
    }
    __syncthreads();
    for (int s = tid; s < nedge; s += 256) stage[gaddr[s]] = sval[s];
}

// exclusive scan of bucket counts -> gbase[NBK+1]; row_start[N] tail;
// FUSED: Wc precompute (att columns for gemm1's 5th MFMA).
__global__ __launch_bounds__(256) void k_bucket_scan(const int* __restrict__ cursor,
                                                     int* __restrict__ gbase,
                                                     int* __restrict__ row_start,
                                                     const float* __restrict__ W1,
                                                     const float* __restrict__ att_src,
                                                     const float* __restrict__ att_dst,
                                                     float* __restrict__ Wc,
                                                     int NBK, int E, int N) {
    __shared__ int sA[512];
    __shared__ int cnt[512];
    int tid = threadIdx.x;
    for (int i = tid; i < 512; i += 256)
        cnt[i] = (i < NBK) ? cursor[i] : 0;
    __syncthreads();
    sA[tid] = cnt[tid]; sA[tid + 256] = cnt[tid + 256];
    __syncthreads();
    for (int off = 1; off < 512; off <<= 1) {
        int r0 = sA[tid] + ((tid >= off) ? sA[tid - off] : 0);
        int r1 = sA[tid + 256] + ((tid + 256 >= off) ? sA[tid + 256 - off] : 0);
        __syncthreads();
        sA[tid] = r0; sA[tid + 256] = r1;
        __syncthreads();
    }
    for (int i = tid; i < 512; i += 256)
        if (i < NBK) gbase[i] = sA[i] - cnt[i];
    if (tid == 0) { gbase[NBK] = E; row_start[N] = E + N; }
    // fused Wc: col 0-3 = att_src heads, 4-7 = att_dst heads, 8-15 = 0
    for (int i = tid; i < 16 * 128; i += 256) {
        int col = i >> 7, k = i & 127;
        float v = 0.f;
        if (col < 8) {
            int h = col & 3;
            const float* att = (col < 4) ? att_src : att_dst;
            #pragma unroll
            for (int c = 0; c < 16; c++) v += W1[k * 64 + h * 16 + c] * att[h * 16 + c];
        }
        Wc[i] = v;
    }
}

// Pass 2: per-bucket fine CSR build (L2-hot window -> dense writeback)
__global__ __launch_bounds__(256) void k_build(const int* __restrict__ stage,
                                               const int* __restrict__ gbase,
                                               int* __restrict__ row_start,
                                               int* __restrict__ csr, int N) {
    __shared__ int cnt[256];
    __shared__ int lb[256];
    __shared__ int cur[256];
    __shared__ int sA[256];
    int b = blockIdx.x, tid = threadIdx.x;
    int nodes0 = b << BSH;
    int nnodes = N - nodes0; if (nnodes > 256) nnodes = 256;
    int ebase = gbase[b];
    int ecnt = gbase[b + 1] - ebase;
    const int* sbk = stage + b * BCAP;
    cnt[tid] = (tid < nnodes) ? 1 : 0;  // self loop
    __syncthreads();
    for (int e = tid; e < ecnt; e += 256) {
        int l = (sbk[e] >> 17) & 255;
        atomicAdd(&cnt[l], 1);
    }
    __syncthreads();
    int myc = cnt[tid];
    sA[tid] = myc;
    __syncthreads();
    for (int off = 1; off < 256; off <<= 1) {
        int r = sA[tid] + ((tid >= off) ? sA[tid - off] : 0);
        __syncthreads();
        sA[tid] = r;
        __syncthreads();
    }
    int gb = ebase + nodes0;
    lb[tid] = sA[tid] - myc;
    cur[tid] = 1;
    __syncthreads();
    if (tid < nnodes) {
        row_start[nodes0 + tid] = gb + lb[tid];
        csr[gb + lb[tid]] = nodes0 + tid;
    }
    __syncthreads();
    for (int e = tid; e < ecnt; e += 256) {
        int v = sbk[e];
        int l = (v >> 17) & 255;
        int src = v & 0x1FFFF;
        int r = atomicAdd(&cur[l], 1);
        csr[gb + lb[l] + r] = src;
    }
}

// h1[N,64](fp16) = x[N,128] @ W1[128,64] via MFMA 16x16x32 bf16 (R9).
__global__ __launch_bounds__(256) void k_gemm1(const float* __restrict__ x,
                                               const float* __restrict__ W1,
                                               const float* __restrict__ Wc,
                                               __half* __restrict__ h1, float* __restrict__ a_src,
                                               float* __restrict__ a_dst, int N) {
    __shared__ short wt[80 * 136];   // cols 0-63: W1^T; cols 64-79: Wc
    int tid = threadIdx.x;
    for (int i = tid; i < 128 * 64; i += 256) {
        int k = i >> 6, c = i & 63;
        wt[c * 136 + k] = f2bf(W1[i]);
    }
    for (int i = tid; i < 16 * 128; i += 256) {
        int col = i >> 7, k = i & 127;
        wt[(64 + col) * 136 + k] = f2bf(Wc[i]);
    }
    __syncthreads();
    int wave = tid >> 6, lane = tid & 63;
    int m = lane & 15, q = lane >> 4;
    int nbase = blockIdx.x * 64 + wave * 16;
    int anode = nbase + m;
    bool rowok = anode < N;
    const float* xrow = x + (size_t)(rowok ? anode : 0) * 128 + q * 8;

    float4v acc[5];
    #pragma unroll
    for (int ct = 0; ct < 5; ct++)
        #pragma unroll
        for (int r = 0; r < 4; r++) acc[ct][r] = 0.f;

    #pragma unroll
    for (int kc = 0; kc < 4; kc++) {
        float4 u0 = make_float4(0.f, 0.f, 0.f, 0.f), u1 = u0;
        if (rowok) {
            u0 = *(const float4*)(xrow + kc * 32);
            u1 = *(const float4*)(xrow + kc * 32 + 4);
        }
        short8 af;
        af[0] = f2bf(u0.x); af[1] = f2bf(u0.y); af[2] = f2bf(u0.z); af[3] = f2bf(u0.w);
        af[4] = f2bf(u1.x); af[5] = f2bf(u1.y); af[6] = f2bf(u1.z); af[7] = f2bf(u1.w);
        #pragma unroll
        for (int ct = 0; ct < 5; ct++) {
            short8 bf = *(const short8*)&wt[(ct * 16 + m) * 136 + kc * 32 + q * 8];
            acc[ct] = __builtin_amdgcn_mfma_f32_16x16x32_bf16(af, bf, acc[ct], 0, 0, 0);
        }
    }
    #pragma unroll
    for (int ct = 0; ct < 4; ct++) {
        #pragma unroll
        for (int r = 0; r < 4; r++) {
            int n = nbase + q * 4 + r;
            if (n < N) h1[(size_t)n * 64 + ct * 16 + m] = __float2half(acc[ct][r]);
        }
    }
    #pragma unroll
    for (int r = 0; r < 4; r++) {
        int n = nbase + q * 4 + r;
        if (n < N) {
            float v = acc[4][r];
            if (m < 4) a_src[n * 4 + m] = v;
            else if (m < 8) a_dst[n * 4 + (m - 4)] = v;
        }
    }
}

// layer-1 aggregation: 4 nodes per wave (16 lanes x 4 channels via 8B loads),
// four independent gather latency chains per wave.
__global__ __launch_bounds__(256) void k_agg1(const int* __restrict__ row_start,
                                              const int* __restrict__ csr_src,
                                              const float* __restrict__ a_src,
                                              const float* __restrict__ a_dst,
                                              const __half* __restrict__ h1,
                                              const float* __restrict__ bias,
                                              float* __restrict__ out1, int N) {
    __shared__ int   sidx[16][CAP1];
    __shared__ float sval[16][CAP1 * 4];
    int tid = threadIdx.x;
    int wave = tid >> 6, lane = tid & 63;
    int quad = lane >> 4, l16 = lane & 15;
    int slot = wave * 4 + quad;
    int node = blockIdx.x * 16 + slot;
    if (node >= N) return;
    int row = row_start[node];
    int deg = row_start[node + 1] - row;
    float4 ad = ((const float4*)a_dst)[node];
    // phase 1: exp + sum (16 lanes per node)
    float s0 = 0.f, s1 = 0.f, s2 = 0.f, s3 = 0.f;
    for (int j = l16; j < deg; j += 16) {
        int s = csr_src[row + j];
        float4 as = ((const float4*)a_src)[s];
        float e0 = __expf(LRELU(as.x + ad.x));
        float e1 = __expf(LRELU(as.y + ad.y));
        float e2 = __expf(LRELU(as.z + ad.z));
        float e3 = __expf(LRELU(as.w + ad.w));
        if (j < CAP1) {
            sidx[slot][j] = s;
            *(float4*)&sval[slot][j * 4] = make_float4(e0, e1, e2, e3);
        }
        s0 += e0; s1 += e1; s2 += e2; s3 += e3;
    }
    #pragma unroll
    for (int m = 1; m < 16; m <<= 1) {
        s0 += __shfl_xor(s0, m, 64);
        s1 += __shfl_xor(s1, m, 64);
        s2 += __shfl_xor(s2, m, 64);
        s3 += __shfl_xor(s3, m, 64);
    }
    // phase 2: lane covers channels l16*4 .. l16*4+3; head = l16>>2
    int myh = l16 >> 2;
    float ssv = myh == 0 ? s0 : myh == 1 ? s1 : myh == 2 ? s2 : s3;
    float adm = myh == 0 ? ad.x : myh == 1 ? ad.y : myh == 2 ? ad.z : ad.w;
    float iv = 1.f / (ssv + 1e-16f);
    float A0 = 0.f, A1 = 0.f, A2 = 0.f, A3 = 0.f;
    float B0 = 0.f, B1 = 0.f, B2 = 0.f, B3 = 0.f;
    int dc = deg < CAP1 ? deg : CAP1;
    int j = 0;
    for (; j + 8 <= dc; j += 8) {
        int t[8]; float e[8]; float2 lo[8], hi[8];
        #pragma unroll
        for (int u = 0; u < 8; u++) {
            t[u] = sidx[slot][j + u];
            e[u] = sval[slot][(j + u) * 4 + myh];
        }
        #pragma unroll
        for (int u = 0; u < 8; u++) {
            union { float2 f; __half2 h[2]; } uu;
            uu.f = *(const float2*)&h1[(size_t)t[u] * 64 + l16 * 4];
            lo[u] = __half22float2(uu.h[0]);
            hi[u] = __half22float2(uu.h[1]);
        }
        #pragma unroll
        for (int u = 0; u < 8; u += 2) {
            A0 += e[u] * lo[u].x; A1 += e[u] * lo[u].y;
            A2 += e[u] * hi[u].x; A3 += e[u] * hi[u].y;
            B0 += e[u + 1] * lo[u + 1].x; B1 += e[u + 1] * lo[u + 1].y;
            B2 += e[u + 1] * hi[u + 1].x; B3 += e[u + 1] * hi[u + 1].y;
        }
    }
    for (; j < dc; j++) {
        int t = sidx[slot][j];
        float e = sval[slot][j * 4 + myh];
        union { float2 f; __half2 h[2]; } uu;
        uu.f = *(const float2*)&h1[(size_t)t * 64 + l16 * 4];
        float2 lo = __half22float2(uu.h[0]), hi = __half22float2(uu.h[1]);
        A0 += e * lo.x; A1 += e * lo.y; A2 += e * hi.x; A3 += e * hi.y;
    }
    for (; j < deg; j++) {   // deg > CAP1 fallback
        int s = csr_src[row + j];
        float e = __expf(LRELU(a_src[s * 4 + myh] + adm));
        union { float2 f; __half2 h[2]; } uu;
        uu.f = *(const float2*)&h1[(size_t)s * 64 + l16 * 4];
        float2 lo = __half22float2(uu.h[0]), hi = __half22float2(uu.h[1]);
        A0 += e * lo.x; A1 += e * lo.y; A2 += e * hi.x; A3 += e * hi.y;
    }
    A0 += B0; A1 += B1; A2 += B2; A3 += B3;
    float4 bb = ((const float4*)bias)[l16];
    float o0 = A0 * iv + bb.x;
    float o1 = A1 * iv + bb.y;
    float o2 = A2 * iv + bb.z;
    float o3 = A3 * iv + bb.w;
    o0 = (o0 > 0.f) ? o0 : (__expf(o0) - 1.f);
    o1 = (o1 > 0.f) ? o1 : (__expf(o1) - 1.f);
    o2 = (o2 > 0.f) ? o2 : (__expf(o2) - 1.f);
    o3 = (o3 > 0.f) ? o3 : (__expf(o3) - 1.f);
    ((float4*)out1)[(size_t)node * 16 + l16] = make_float4(o0, o1, o2, o3);
}

// h2[N,16](fp16) = out1[N,64] @ W2[64,16]; fused att2 dots
__global__ __launch_bounds__(256) void k_gemm2(const float* __restrict__ out1,
                                               const float* __restrict__ W2,
                                               const float* __restrict__ att_src,
                                               const float* __restrict__ att_dst,
                                               __half* __restrict__ h2, float* __restrict__ a_src,
                                               float* __restrict__ a_dst, int N) {
    __shared__ float ws[64 * 16];
    __shared__ float xs[16 * 65];
    int tid = threadIdx.x;
    for (int i = tid; i < 64 * 16; i += 256) ws[i] = W2[i];
    int n0 = blockIdx.x * 16;
    for (int i = tid; i < 16 * 64; i += 256) {
        int r = i >> 6, c = i & 63;
        int n = n0 + r;
        xs[r * 65 + c] = (n < N) ? out1[(size_t)n * 64 + c] : 0.f;
    }
    __syncthreads();
    int nl = tid >> 4, c = tid & 15;
    int n = n0 + nl;
    float acc = 0.f;
    #pragma unroll
    for (int k = 0; k < 64; k++) acc += xs[nl * 65 + k] * ws[k * 16 + c];
    float asv = acc * att_src[c];
    float adv = acc * att_dst[c];
    #pragma unroll
    for (int m = 1; m < 16; m <<= 1) {
        asv += __shfl_xor(asv, m, 64);
        adv += __shfl_xor(adv, m, 64);
    }
    if (n < N) {
        h2[(size_t)n * 16 + c] = __float2half(acc);
        if (c == 0) { a_src[n] = asv; a_dst[n] = adv; }
    }
}

// layer-2 aggregation + bias + log_softmax; 4 nodes/wave, fp16 h2 gathers
__global__ __launch_bounds__(256) void k_agg2(const int* __restrict__ row_start,
                                              const int* __restrict__ csr_src,
                                              const float* __restrict__ a_src,
                                              const float* __restrict__ a_dst,
                                              const __half* __restrict__ h2,
                                              const float* __restrict__ bias,
                                              float* __restrict__ out, int N) {
    __shared__ int   sidx[16][CAP2];
    __shared__ float sval[16][CAP2];
    int tid = threadIdx.x;
    int wave = tid >> 6, lane = tid & 63;
    int quad = lane >> 4, l16 = lane & 15;
    int slot = wave * 4 + quad;
    int node = blockIdx.x * 16 + slot;
    if (node >= N) return;
    int row = row_start[node];
    int deg = row_start[node + 1] - row;
    float ad = a_dst[node];
    float sh = 0.f;
    for (int j = l16; j < deg; j += 16) {
        int s = csr_src[row + j];
        float e = __expf(LRELU(a_src[s] + ad));
        if (j < CAP2) { sidx[slot][j] = s; sval[slot][j] = e; }
        sh += e;
    }
    #pragma unroll
    for (int m = 1; m < 16; m <<= 1) sh += __shfl_xor(sh, m, 64);
    float iv = 1.f / (sh + 1e-16f);
    // gather: lane = cg(0..7 channel pair) x eg(0..1 edge slot)
    int cg = l16 & 7, eg = l16 >> 3;
    float ax = 0.f, ay = 0.f, bx = 0.f, by = 0.f;
    int dc = deg < CAP2 ? deg : CAP2;
    int j = eg;
    for (; j + 6 < dc; j += 8) {
        int t0 = sidx[slot][j], t1 = sidx[slot][j + 2];
        int t2 = sidx[slot][j + 4], t3 = sidx[slot][j + 6];
        float e0 = sval[slot][j], e1 = sval[slot][j + 2];
        float e2 = sval[slot][j + 4], e3 = sval[slot][j + 6];
        float2 g0 = __half22float2(*(const __half2*)&h2[(size_t)t0 * 16 + cg * 2]);
        float2 g1 = __half22float2(*(const __half2*)&h2[(size_t)t1 * 16 + cg * 2]);
        float2 g2 = __half22float2(*(const __half2*)&h2[(size_t)t2 * 16 + cg * 2]);
        float2 g3 = __half22float2(*(const __half2*)&h2[(size_t)t3 * 16 + cg * 2]);
        ax += e0 * g0.x + e2 * g2.x; ay += e0 * g0.y + e2 * g2.y;
        bx += e1 * g1.x + e3 * g3.x; by += e1 * g1.y + e3 * g3.y;
    }
    for (; j < deg; j += 2) {
        int s; float e;
        if (j < dc) { s = sidx[slot][j]; e = sval[slot][j]; }
        else { s = csr_src[row + j]; e = __expf(LRELU(a_src[s] + ad)); }
        float2 g = __half22float2(*(const __half2*)&h2[(size_t)s * 16 + cg * 2]);
        ax += e * g.x; ay += e * g.y;
    }
    ax += bx; ay += by;
    ax += __shfl_xor(ax, 8, 64);   // combine the 2 edge subgroups
    ay += __shfl_xor(ay, 8, 64);
    float2 bb = ((const float2*)bias)[cg];
    float vx = ax * iv + bb.x;
    float vy = ay * iv + bb.y;
    // log_softmax over 16 channels (pairs across lanes cg=0..7)
    float mx = fmaxf(vx, vy);
    #pragma unroll
    for (int m = 1; m < 8; m <<= 1) mx = fmaxf(mx, __shfl_xor(mx, m, 64));
    float se = __expf(vx - mx) + __expf(vy - mx);
    #pragma unroll
    for (int m = 1; m < 8; m <<= 1) se += __shfl_xor(se, m, 64);
    float ls = mx + __logf(se);
    if (eg == 0)
        ((float2*)out)[(size_t)node * 8 + cg] = make_float2(vx - ls, vy - ls);
}

extern "C" void kernel_launch(void* const* d_in, const int* in_sizes, int n_in,
                              void* d_out, int out_size, void* d_ws, size_t ws_size,
                              hipStream_t stream) {
    const float* x        = (const float*)d_in[0];
    const int*   ei       = (const int*)d_in[1];
    const float* W1       = (const float*)d_in[2];
    const float* att_src1 = (const float*)d_in[3];
    const float* att_dst1 = (const float*)d_in[4];
    const float* bias1    = (const float*)d_in[5];
    const float* W2       = (const float*)d_in[6];
    const float* att_src2 = (const float*)d_in[7];
    const float* att_dst2 = (const float*)d_in[8];
    const float* bias2    = (const float*)d_in[9];
    float* out = (float*)d_out;

    const int N = in_sizes[0] / 128;
    const int E = in_sizes[1] / 2;
    const int NBK = (N + 255) >> BSH;

    char* p = (char*)d_ws;
    auto alloc = [&](size_t bytes) -> void* {
        void* r = (void*)p;
        p += (bytes + 255) & ~(size_t)255;
        return r;
    };
    __half* h1     = (__half*)alloc((size_t)N * 64 * 2);
    float* out1    = (float*)alloc((size_t)N * 64 * 4);
    __half* h2     = (__half*)alloc((size_t)N * 16 * 2);
    float* a_src1  = (float*)alloc((size_t)N * 4 * 4);
    float* a_dst1  = (float*)alloc((size_t)N * 4 * 4);
    float* a_src2  = (float*)alloc((size_t)N * 4);
    float* a_dst2  = (float*)alloc((size_t)N * 4);
    float* Wc      = (float*)alloc(16 * 128 * 4);
    int*   row_st  = (int*)alloc((size_t)(N + 1) * 4);
    int*   csr     = (int*)alloc((size_t)(E + N) * 4);
    int*   stage   = (int*)alloc((size_t)NBK * BCAP * 4);
    int*   cursor  = (int*)alloc((size_t)NBK * 4);
    int*   gbase   = (int*)alloc((size_t)(NBK + 1) * 4);
    (void)ws_size; (void)n_in; (void)out_size;

    hipMemsetAsync(cursor, 0, (size_t)NBK * 4, stream);
    k_scatter<<<(E + CHK - 1) / CHK, 256, 0, stream>>>(ei, cursor, stage, E, NBK);
    k_bucket_scan<<<1, 256, 0, stream>>>(cursor, gbase, row_st, W1, att_src1, att_dst1, Wc,
                                         NBK, E, N);
    k_build<<<NBK, 256, 0, stream>>>(stage, gbase, row_st, csr, N);
    k_gemm1<<<(N + 63) / 64, 256, 0, stream>>>(x, W1, Wc, h1, a_src1, a_dst1, N);
    k_agg1<<<(N + 15) / 16, 256, 0, stream>>>(row_st, csr, a_src1, a_dst1, h1, bias1, out1, N);
    k_gemm2<<<(N + 15) / 16, 256, 0, stream>>>(out1, W2, att_src2, att_dst2, h2, a_src2, a_dst2, N);
    k_agg2<<<(N + 15) / 16, 256, 0, stream>>>(row_st, csr, a_src2, a_dst2, h2, bias2, out, N);
}

// Round 12
// 256.458 us; speedup vs baseline: 1.1844x; 1.0062x over previous
//
#include <hip/hip_runtime.h>
#include <hip/hip_fp16.h>
#include <hip/hip_bf16.h>
#include <math.h>

// GAT 2-layer forward, MI355X. FP32 in/out, int32 edge_index.
// R12: consolidation — k_bucket_scan folded into k_build (per-block bucket
// prefix + Wc in block 0), k_scatter drops sdst LDS (26KB -> 6 blocks/CU).
// agg1/agg2 (4 nodes/wave), MFMA gemm1, gemm2 unchanged from R11.

#define LRELU(v) ((v) > 0.f ? (v) : 0.2f * (v))
#define BSH 8            // 256 nodes per bucket
#define BCAP 5120        // staged capacity per bucket
#define CHK 2048         // edges per k_scatter block
#define CAP1 64          // agg1 LDS edge cache per node
#define CAP2 64          // agg2 LDS edge cache per node

typedef __attribute__((ext_vector_type(8))) short short8;
typedef __attribute__((ext_vector_type(4))) float float4v;

static __device__ __forceinline__ short f2bf(float f) {
    __hip_bfloat16 b = __float2bfloat16(f);
    return *reinterpret_cast<short*>(&b);
}

// Pass 1: bin edges by dst bucket, stage reordered in LDS, flush dense runs.
__global__ __launch_bounds__(256) void k_scatter(const int* __restrict__ ei, int* __restrict__ cursor,
                                                 int* __restrict__ stage, int E, int NBK) {
    __shared__ int sval[CHK];
    __shared__ int gaddr[CHK];
    __shared__ int hist[512];
    __shared__ int lbase[512];
    __shared__ int cnt2[512];
    __shared__ int gdelta[512];
    __shared__ int sA[512];
    int tid = threadIdx.x;
    int e0 = blockIdx.x * CHK;
    int nedge = E - e0; if (nedge > CHK) nedge = CHK;

    for (int i = tid; i < 512; i += 256) { hist[i] = 0; cnt2[i] = 0; }
    __syncthreads();
    for (int j = tid; j < nedge; j += 256) {
        int d = ei[E + e0 + j];
        atomicAdd(&hist[d >> BSH], 1);
    }
    __syncthreads();
    sA[tid] = hist[tid]; sA[tid + 256] = hist[tid + 256];
    __syncthreads();
    for (int off = 1; off < 512; off <<= 1) {
        int r0 = sA[tid] + ((tid >= off) ? sA[tid - off] : 0);
        int r1 = sA[tid + 256] + ((tid + 256 >= off) ? sA[tid + 256 - off] : 0);
        __syncthreads();
        sA[tid] = r0; sA[tid + 256] = r1;
        __syncthreads();
    }
    for (int i = tid; i < 512; i += 256) lbase[i] = sA[i] - hist[i];
    __syncthreads();
    for (int b = tid; b < NBK; b += 256) {
        int c = hist[b];
        if (c > 0) {
            int rel = atomicAdd(&cursor[b], c);
            gdelta[b] = b * BCAP + rel - lbase[b];
        }
    }
    __syncthreads();
    for (int j = tid; j < nedge; j += 256) {
        int s = ei[e0 + j];
        int d = ei[E + e0 + j];          // L2-hot re-read (saves 8KB LDS)
        int b = d >> BSH;
        int r = atomicAdd(&cnt2[b], 1);
        int slot = lbase[b] + r;
        sval[slot]  = s | ((d & ((1 << BSH) - 1)) << 17);
        gaddr[slot] = gdelta[b] + slot;
    }
    __syncthreads();
    for (int s = tid; s < nedge; s += 256) stage[gaddr[s]] = sval[s];
}

// Pass 2: per-bucket fine CSR build. Each block computes its own bucket
// prefix from cursor[] (<=NBK int reads). Block 0 also writes row_start[N]
// and precomputes Wc (att columns for gemm1's 5th MFMA).
__global__ __launch_bounds__(256) void k_build(const int* __restrict__ stage,
                                               const int* __restrict__ cursor,
                                               int* __restrict__ row_start,
                                               int* __restrict__ csr,
                                               const float* __restrict__ W1,
                                               const float* __restrict__ att_src,
                                               const float* __restrict__ att_dst,
                                               float* __restrict__ Wc,
                                               int NBK, int E, int N) {
    __shared__ int cnt[256];
    __shared__ int lb[256];
    __shared__ int cur[256];
    __shared__ int sA[256];
    int b = blockIdx.x, tid = threadIdx.x;
    int nodes0 = b << BSH;
    int nnodes = N - nodes0; if (nnodes > 256) nnodes = 256;
    // bucket prefix: ebase = sum cursor[0..b-1]
    int partial = 0;
    for (int i = tid; i < b; i += 256) partial += cursor[i];
    sA[tid] = partial;
    __syncthreads();
    for (int off = 128; off >= 1; off >>= 1) {
        if (tid < off) sA[tid] += sA[tid + off];
        __syncthreads();
    }
    int ebase = sA[0];
    int ecnt = cursor[b];
    __syncthreads();
    if (b == 0) {
        if (tid == 0) row_start[N] = E + N;
        // Wc: col 0-3 = att_src heads, 4-7 = att_dst heads, 8-15 = 0
        for (int i = tid; i < 16 * 128; i += 256) {
            int col = i >> 7, k = i & 127;
            float v = 0.f;
            if (col < 8) {
                int h = col & 3;
                const float* att = (col < 4) ? att_src : att_dst;
                #pragma unroll
                for (int c = 0; c < 16; c++) v += W1[k * 64 + h * 16 + c] * att[h * 16 + c];
            }
            Wc[i] = v;
        }
    }
    const int* sbk = stage + b * BCAP;
    cnt[tid] = (tid < nnodes) ? 1 : 0;  // self loop
    __syncthreads();
    for (int e = tid; e < ecnt; e += 256) {
        int l = (sbk[e] >> 17) & 255;
        atomicAdd(&cnt[l], 1);
    }
    __syncthreads();
    int myc = cnt[tid];
    sA[tid] = myc;
    __syncthreads();
    for (int off = 1; off < 256; off <<= 1) {
        int r = sA[tid] + ((tid >= off) ? sA[tid - off] : 0);
        __syncthreads();
        sA[tid] = r;
        __syncthreads();
    }
    int gb = ebase + nodes0;
    lb[tid] = sA[tid] - myc;
    cur[tid] = 1;
    __syncthreads();
    if (tid < nnodes) {
        row_start[nodes0 + tid] = gb + lb[tid];
        csr[gb + lb[tid]] = nodes0 + tid;
    }
    __syncthreads();
    for (int e = tid; e < ecnt; e += 256) {
        int v = sbk[e];
        int l = (v >> 17) & 255;
        int src = v & 0x1FFFF;
        int r = atomicAdd(&cur[l], 1);
        csr[gb + lb[l] + r] = src;
    }
}

// h1[N,64](fp16) = x[N,128] @ W1[128,64] via MFMA 16x16x32 bf16 (R9).
__global__ __launch_bounds__(256) void k_gemm1(const float* __restrict__ x,
                                               const float* __restrict__ W1,
                                               const float* __restrict__ Wc,
                                               __half* __restrict__ h1, float* __restrict__ a_src,
                                               float* __restrict__ a_dst, int N) {
    __shared__ short wt[80 * 136];   // cols 0-63: W1^T; cols 64-79: Wc
    int tid = threadIdx.x;
    for (int i = tid; i < 128 * 64; i += 256) {
        int k = i >> 6, c = i & 63;
        wt[c * 136 + k] = f2bf(W1[i]);
    }
    for (int i = tid; i < 16 * 128; i += 256) {
        int col = i >> 7, k = i & 127;
        wt[(64 + col) * 136 + k] = f2bf(Wc[i]);
    }
    __syncthreads();
    int wave = tid >> 6, lane = tid & 63;
    int m = lane & 15, q = lane >> 4;
    int nbase = blockIdx.x * 64 + wave * 16;
    int anode = nbase + m;
    bool rowok = anode < N;
    const float* xrow = x + (size_t)(rowok ? anode : 0) * 128 + q * 8;

    float4v acc[5];
    #pragma unroll
    for (int ct = 0; ct < 5; ct++)
        #pragma unroll
        for (int r = 0; r < 4; r++) acc[ct][r] = 0.f;

    #pragma unroll
    for (int kc = 0; kc < 4; kc++) {
        float4 u0 = make_float4(0.f, 0.f, 0.f, 0.f), u1 = u0;
        if (rowok) {
            u0 = *(const float4*)(xrow + kc * 32);
            u1 = *(const float4*)(xrow + kc * 32 + 4);
        }
        short8 af;
        af[0] = f2bf(u0.x); af[1] = f2bf(u0.y); af[2] = f2bf(u0.z); af[3] = f2bf(u0.w);
        af[4] = f2bf(u1.x); af[5] = f2bf(u1.y); af[6] = f2bf(u1.z); af[7] = f2bf(u1.w);
        #pragma unroll
        for (int ct = 0; ct < 5; ct++) {
            short8 bf = *(const short8*)&wt[(ct * 16 + m) * 136 + kc * 32 + q * 8];
            acc[ct] = __builtin_amdgcn_mfma_f32_16x16x32_bf16(af, bf, acc[ct], 0, 0, 0);
        }
    }
    #pragma unroll
    for (int ct = 0; ct < 4; ct++) {
        #pragma unroll
        for (int r = 0; r < 4; r++) {
            int n = nbase + q * 4 + r;
            if (n < N) h1[(size_t)n * 64 + ct * 16 + m] = __float2half(acc[ct][r]);
        }
    }
    #pragma unroll
    for (int r = 0; r < 4; r++) {
        int n = nbase + q * 4 + r;
        if (n < N) {
            float v = acc[4][r];
            if (m < 4) a_src[n * 4 + m] = v;
            else if (m < 8) a_dst[n * 4 + (m - 4)] = v;
        }
    }
}

// layer-1 aggregation: 4 nodes per wave (16 lanes x 4 channels via 8B loads)
__global__ __launch_bounds__(256) void k_agg1(const int* __restrict__ row_start,
                                              const int* __restrict__ csr_src,
                                              const float* __restrict__ a_src,
                                              const float* __restrict__ a_dst,
                                              const __half* __restrict__ h1,
                                              const float* __restrict__ bias,
                                              float* __restrict__ out1, int N) {
    __shared__ int   sidx[16][CAP1];
    __shared__ float sval[16][CAP1 * 4];
    int tid = threadIdx.x;
    int wave = tid >> 6, lane = tid & 63;
    int quad = lane >> 4, l16 = lane & 15;
    int slot = wave * 4 + quad;
    int node = blockIdx.x * 16 + slot;
    if (node >= N) return;
    int row = row_start[node];
    int deg = row_start[node + 1] - row;
    float4 ad = ((const float4*)a_dst)[node];
    float s0 = 0.f, s1 = 0.f, s2 = 0.f, s3 = 0.f;
    for (int j = l16; j < deg; j += 16) {
        int s = csr_src[row + j];
        float4 as = ((const float4*)a_src)[s];
        float e0 = __expf(LRELU(as.x + ad.x));
        float e1 = __expf(LRELU(as.y + ad.y));
        float e2 = __expf(LRELU(as.z + ad.z));
        float e3 = __expf(LRELU(as.w + ad.w));
        if (j < CAP1) {
            sidx[slot][j] = s;
            *(float4*)&sval[slot][j * 4] = make_float4(e0, e1, e2, e3);
        }
        s0 += e0; s1 += e1; s2 += e2; s3 += e3;
    }
    #pragma unroll
    for (int m = 1; m < 16; m <<= 1) {
        s0 += __shfl_xor(s0, m, 64);
        s1 += __shfl_xor(s1, m, 64);
        s2 += __shfl_xor(s2, m, 64);
        s3 += __shfl_xor(s3, m, 64);
    }
    int myh = l16 >> 2;
    float ssv = myh == 0 ? s0 : myh == 1 ? s1 : myh == 2 ? s2 : s3;
    float adm = myh == 0 ? ad.x : myh == 1 ? ad.y : myh == 2 ? ad.z : ad.w;
    float iv = 1.f / (ssv + 1e-16f);
    float A0 = 0.f, A1 = 0.f, A2 = 0.f, A3 = 0.f;
    float B0 = 0.f, B1 = 0.f, B2 = 0.f, B3 = 0.f;
    int dc = deg < CAP1 ? deg : CAP1;
    int j = 0;
    for (; j + 8 <= dc; j += 8) {
        int t[8]; float e[8]; float2 lo[8], hi[8];
        #pragma unroll
        for (int u = 0; u < 8; u++) {
            t[u] = sidx[slot][j + u];
            e[u] = sval[slot][(j + u) * 4 + myh];
        }
        #pragma unroll
        for (int u = 0; u < 8; u++) {
            union { float2 f; __half2 h[2]; } uu;
            uu.f = *(const float2*)&h1[(size_t)t[u] * 64 + l16 * 4];
            lo[u] = __half22float2(uu.h[0]);
            hi[u] = __half22float2(uu.h[1]);
        }
        #pragma unroll
        for (int u = 0; u < 8; u += 2) {
            A0 += e[u] * lo[u].x; A1 += e[u] * lo[u].y;
            A2 += e[u] * hi[u].x; A3 += e[u] * hi[u].y;
            B0 += e[u + 1] * lo[u + 1].x; B1 += e[u + 1] * lo[u + 1].y;
            B2 += e[u + 1] * hi[u + 1].x; B3 += e[u + 1] * hi[u + 1].y;
        }
    }
    for (; j < dc; j++) {
        int t = sidx[slot][j];
        float e = sval[slot][j * 4 + myh];
        union { float2 f; __half2 h[2]; } uu;
        uu.f = *(const float2*)&h1[(size_t)t * 64 + l16 * 4];
        float2 lo = __half22float2(uu.h[0]), hi = __half22float2(uu.h[1]);
        A0 += e * lo.x; A1 += e * lo.y; A2 += e * hi.x; A3 += e * hi.y;
    }
    for (; j < deg; j++) {   // deg > CAP1 fallback
        int s = csr_src[row + j];
        float e = __expf(LRELU(a_src[s * 4 + myh] + adm));
        union { float2 f; __half2 h[2]; } uu;
        uu.f = *(const float2*)&h1[(size_t)s * 64 + l16 * 4];
        float2 lo = __half22float2(uu.h[0]), hi = __half22float2(uu.h[1]);
        A0 += e * lo.x; A1 += e * lo.y; A2 += e * hi.x; A3 += e * hi.y;
    }
    A0 += B0; A1 += B1; A2 += B2; A3 += B3;
    float4 bb = ((const float4*)bias)[l16];
    float o0 = A0 * iv + bb.x;
    float o1 = A1 * iv + bb.y;
    float o2 = A2 * iv + bb.z;
    float o3 = A3 * iv + bb.w;
    o0 = (o0 > 0.f) ? o0 : (__expf(o0) - 1.f);
    o1 = (o1 > 0.f) ? o1 : (__expf(o1) - 1.f);
    o2 = (o2 > 0.f) ? o2 : (__expf(o2) - 1.f);
    o3 = (o3 > 0.f) ? o3 : (__expf(o3) - 1.f);
    ((float4*)out1)[(size_t)node * 16 + l16] = make_float4(o0, o1, o2, o3);
}

// h2[N,16](fp16) = out1[N,64] @ W2[64,16]; fused att2 dots
__global__ __launch_bounds__(256) void k_gemm2(const float* __restrict__ out1,
                                               const float* __restrict__ W2,
                                               const float* __restrict__ att_src,
                                               const float* __restrict__ att_dst,
                                               __half* __restrict__ h2, float* __restrict__ a_src,
                                               float* __restrict__ a_dst, int N) {
    __shared__ float ws[64 * 16];
    __shared__ float xs[16 * 65];
    int tid = threadIdx.x;
    for (int i = tid; i < 64 * 16; i += 256) ws[i] = W2[i];
    int n0 = blockIdx.x * 16;
    for (int i = tid; i < 16 * 64; i += 256) {
        int r = i >> 6, c = i & 63;
        int n = n0 + r;
        xs[r * 65 + c] = (n < N) ? out1[(size_t)n * 64 + c] : 0.f;
    }
    __syncthreads();
    int nl = tid >> 4, c = tid & 15;
    int n = n0 + nl;
    float acc = 0.f;
    #pragma unroll
    for (int k = 0; k < 64; k++) acc += xs[nl * 65 + k] * ws[k * 16 + c];
    float asv = acc * att_src[c];
    float adv = acc * att_dst[c];
    #pragma unroll
    for (int m = 1; m < 16; m <<= 1) {
        asv += __shfl_xor(asv, m, 64);
        adv += __shfl_xor(adv, m, 64);
    }
    if (n < N) {
        h2[(size_t)n * 16 + c] = __float2half(acc);
        if (c == 0) { a_src[n] = asv; a_dst[n] = adv; }
    }
}

// layer-2 aggregation + bias + log_softmax; 4 nodes/wave, fp16 h2 gathers
__global__ __launch_bounds__(256) void k_agg2(const int* __restrict__ row_start,
                                              const int* __restrict__ csr_src,
                                              const float* __restrict__ a_src,
                                              const float* __restrict__ a_dst,
                                              const __half* __restrict__ h2,
                                              const float* __restrict__ bias,
                                              float* __restrict__ out, int N) {
    __shared__ int   sidx[16][CAP2];
    __shared__ float sval[16][CAP2];
    int tid = threadIdx.x;
    int wave = tid >> 6, lane = tid & 63;
    int quad = lane >> 4, l16 = lane & 15;
    int slot = wave * 4 + quad;
    int node = blockIdx.x * 16 + slot;
    if (node >= N) return;
    int row = row_start[node];
    int deg = row_start[node + 1] - row;
    float ad = a_dst[node];
    float sh = 0.f;
    for (int j = l16; j < deg; j += 16) {
        int s = csr_src[row + j];
        float e = __expf(LRELU(a_src[s] + ad));
        if (j < CAP2) { sidx[slot][j] = s; sval[slot][j] = e; }
        sh += e;
    }
    #pragma unroll
    for (int m = 1; m < 16; m <<= 1) sh += __shfl_xor(sh, m, 64);
    float iv = 1.f / (sh + 1e-16f);
    int cg = l16 & 7, eg = l16 >> 3;
    float ax = 0.f, ay = 0.f, bx = 0.f, by = 0.f;
    int dc = deg < CAP2 ? deg : CAP2;
    int j = eg;
    for (; j + 6 < dc; j += 8) {
        int t0 = sidx[slot][j], t1 = sidx[slot][j + 2];
        int t2 = sidx[slot][j + 4], t3 = sidx[slot][j + 6];
        float e0 = sval[slot][j], e1 = sval[slot][j + 2];
        float e2 = sval[slot][j + 4], e3 = sval[slot][j + 6];
        float2 g0 = __half22float2(*(const __half2*)&h2[(size_t)t0 * 16 + cg * 2]);
        float2 g1 = __half22float2(*(const __half2*)&h2[(size_t)t1 * 16 + cg * 2]);
        float2 g2 = __half22float2(*(const __half2*)&h2[(size_t)t2 * 16 + cg * 2]);
        float2 g3 = __half22float2(*(const __half2*)&h2[(size_t)t3 * 16 + cg * 2]);
        ax += e0 * g0.x + e2 * g2.x; ay += e0 * g0.y + e2 * g2.y;
        bx += e1 * g1.x + e3 * g3.x; by += e1 * g1.y + e3 * g3.y;
    }
    for (; j < deg; j += 2) {
        int s; float e;
        if (j < dc) { s = sidx[slot][j]; e = sval[slot][j]; }
        else { s = csr_src[row + j]; e = __expf(LRELU(a_src[s] + ad)); }
        float2 g = __half22float2(*(const __half2*)&h2[(size_t)s * 16 + cg * 2]);
        ax += e * g.x; ay += e * g.y;
    }
    ax += bx; ay += by;
    ax += __shfl_xor(ax, 8, 64);
    ay += __shfl_xor(ay, 8, 64);
    float2 bb = ((const float2*)bias)[cg];
    float vx = ax * iv + bb.x;
    float vy = ay * iv + bb.y;
    float mx = fmaxf(vx, vy);
    #pragma unroll
    for (int m = 1; m < 8; m <<= 1) mx = fmaxf(mx, __shfl_xor(mx, m, 64));
    float se = __expf(vx - mx) + __expf(vy - mx);
    #pragma unroll
    for (int m = 1; m < 8; m <<= 1) se += __shfl_xor(se, m, 64);
    float ls = mx + __logf(se);
    if (eg == 0)
        ((float2*)out)[(size_t)node * 8 + cg] = make_float2(vx - ls, vy - ls);
}

extern "C" void kernel_launch(void* const* d_in, const int* in_sizes, int n_in,
                              void* d_out, int out_size, void* d_ws, size_t ws_size,
                              hipStream_t stream) {
    const float* x        = (const float*)d_in[0];
    const int*   ei       = (const int*)d_in[1];
    const float* W1       = (const float*)d_in[2];
    const float* att_src1 = (const float*)d_in[3];
    const float* att_dst1 = (const float*)d_in[4];
    const float* bias1    = (const float*)d_in[5];
    const float* W2       = (const float*)d_in[6];
    const float* att_src2 = (const float*)d_in[7];
    const float* att_dst2 = (const float*)d_in[8];
    const float* bias2    = (const float*)d_in[9];
    float* out = (float*)d_out;

    const int N = in_sizes[0] / 128;
    const int E = in_sizes[1] / 2;
    const int NBK = (N + 255) >> BSH;

    char* p = (char*)d_ws;
    auto alloc = [&](size_t bytes) -> void* {
        void* r = (void*)p;
        p += (bytes + 255) & ~(size_t)255;
        return r;
    };
    __half* h1     = (__half*)alloc((size_t)N * 64 * 2);
    float* out1    = (float*)alloc((size_t)N * 64 * 4);
    __half* h2     = (__half*)alloc((size_t)N * 16 * 2);
    float* a_src1  = (float*)alloc((size_t)N * 4 * 4);
    float* a_dst1  = (float*)alloc((size_t)N * 4 * 4);
    float* a_src2  = (float*)alloc((size_t)N * 4);
    float* a_dst2  = (float*)alloc((size_t)N * 4);
    float* Wc      = (float*)alloc(16 * 128 * 4);
    int*   row_st  = (int*)alloc((size_t)(N + 1) * 4);
    int*   csr     = (int*)alloc((size_t)(E + N) * 4);
    int*   stage   = (int*)alloc((size_t)NBK * BCAP * 4);
    int*   cursor  = (int*)alloc((size_t)NBK * 4);
    (void)ws_size; (void)n_in; (void)out_size;

    hipMemsetAsync(cursor, 0, (size_t)NBK * 4, stream);
    k_scatter<<<(E + CHK - 1) / CHK, 256, 0, stream>>>(ei, cursor, stage, E, NBK);
    k_build<<<NBK, 256, 0, stream>>>(stage, cursor, row_st, csr,
                                     W1, att_src1, att_dst1, Wc, NBK, E, N);
    k_gemm1<<<(N + 63) / 64, 256, 0, stream>>>(x, W1, Wc, h1, a_src1, a_dst1, N);
    k_agg1<<<(N + 15) / 16, 256, 0, stream>>>(row_st, csr, a_src1, a_dst1, h1, bias1, out1, N);
    k_gemm2<<<(N + 15) / 16, 256, 0, stream>>>(out1, W2, att_src2, att_dst2, h2, a_src2, a_dst2, N);
    k_agg2<<<(N + 15) / 16, 256, 0, stream>>>(row_st, csr, a_src2, a_dst2, h2, bias2, out, N);
}

// Round 13
// 236.561 us; speedup vs baseline: 1.2840x; 1.0841x over previous
//
#include <hip/hip_runtime.h>
#include <hip/hip_fp16.h>
#include <hip/hip_bf16.h>
#include <math.h>

// GAT 2-layer forward, MI355X. FP32 in/out, int32 edge_index.
// R13: scan-free k_scatter (direct per-bucket-run writes, CHK 8192, 6KB LDS);
// gemm2 via MFMA f16 with folded att2 columns (Wc2/Wd2 from k_build blk 0);
// out1 stored fp16. agg1/agg2/gemm1/build core unchanged from R12.

#define LRELU(v) ((v) > 0.f ? (v) : 0.2f * (v))
#define BSH 8            // 256 nodes per bucket
#define BCAP 5120        // staged capacity per bucket
#define CHK 8192         // edges per k_scatter block
#define CAP1 64          // agg1 LDS edge cache per node
#define CAP2 64          // agg2 LDS edge cache per node

typedef __attribute__((ext_vector_type(8))) short short8;
typedef __attribute__((ext_vector_type(8))) _Float16 half8;
typedef __attribute__((ext_vector_type(4))) float float4v;

static __device__ __forceinline__ short f2bf(float f) {
    __hip_bfloat16 b = __float2bfloat16(f);
    return *reinterpret_cast<short*>(&b);
}

// Pass 1 (scan-free): histogram -> reserve per-bucket global runs -> direct
// writes into contiguous runs. No LDS reorder, no prefix scans.
__global__ __launch_bounds__(256) void k_scatter(const int* __restrict__ ei, int* __restrict__ cursor,
                                                 int* __restrict__ stage, int E, int NBK) {
    __shared__ int hist[512];
    __shared__ int cnt2[512];
    __shared__ int base[512];
    int tid = threadIdx.x;
    int e0 = blockIdx.x * CHK;
    int nedge = E - e0; if (nedge > CHK) nedge = CHK;

    for (int i = tid; i < 512; i += 256) { hist[i] = 0; cnt2[i] = 0; }
    __syncthreads();
    for (int j = tid; j < nedge; j += 256) {
        int d = ei[E + e0 + j];
        atomicAdd(&hist[d >> BSH], 1);
    }
    __syncthreads();
    for (int b = tid; b < NBK; b += 256) {
        int c = hist[b];
        if (c > 0) base[b] = b * BCAP + atomicAdd(&cursor[b], c);
    }
    __syncthreads();
    for (int j = tid; j < nedge; j += 256) {
        int s = ei[e0 + j];
        int d = ei[E + e0 + j];
        int b = d >> BSH;
        int r = atomicAdd(&cnt2[b], 1);
        stage[base[b] + r] = s | ((d & ((1 << BSH) - 1)) << 17);
    }
}

// Pass 2: per-bucket fine CSR build. Block 0 also writes row_start[N],
// Wc (gemm1 att columns) and Wc2/Wd2 (gemm2 att columns).
__global__ __launch_bounds__(256) void k_build(const int* __restrict__ stage,
                                               const int* __restrict__ cursor,
                                               int* __restrict__ row_start,
                                               int* __restrict__ csr,
                                               const float* __restrict__ W1,
                                               const float* __restrict__ att_src,
                                               const float* __restrict__ att_dst,
                                               float* __restrict__ Wc,
                                               const float* __restrict__ W2,
                                               const float* __restrict__ att_src2,
                                               const float* __restrict__ att_dst2,
                                               float* __restrict__ Wc2,
                                               int NBK, int E, int N) {
    __shared__ int cnt[256];
    __shared__ int lb[256];
    __shared__ int cur[256];
    __shared__ int sA[256];
    int b = blockIdx.x, tid = threadIdx.x;
    int nodes0 = b << BSH;
    int nnodes = N - nodes0; if (nnodes > 256) nnodes = 256;
    int partial = 0;
    for (int i = tid; i < b; i += 256) partial += cursor[i];
    sA[tid] = partial;
    __syncthreads();
    for (int off = 128; off >= 1; off >>= 1) {
        if (tid < off) sA[tid] += sA[tid + off];
        __syncthreads();
    }
    int ebase = sA[0];
    int ecnt = cursor[b];
    __syncthreads();
    if (b == 0) {
        if (tid == 0) row_start[N] = E + N;
        for (int i = tid; i < 16 * 128; i += 256) {
            int col = i >> 7, k = i & 127;
            float v = 0.f;
            if (col < 8) {
                int h = col & 3;
                const float* att = (col < 4) ? att_src : att_dst;
                #pragma unroll
                for (int c = 0; c < 16; c++) v += W1[k * 64 + h * 16 + c] * att[h * 16 + c];
            }
            Wc[i] = v;
        }
        // Wc2: col0 = W2@att_src2 (64), col1 = W2@att_dst2 (64)
        for (int i = tid; i < 128; i += 256) {
            int col = i >> 6, k = i & 63;
            const float* att = col ? att_dst2 : att_src2;
            float v = 0.f;
            #pragma unroll
            for (int c = 0; c < 16; c++) v += W2[k * 16 + c] * att[c];
            Wc2[i] = v;
        }
    }
    const int* sbk = stage + b * BCAP;
    cnt[tid] = (tid < nnodes) ? 1 : 0;  // self loop
    __syncthreads();
    for (int e = tid; e < ecnt; e += 256) {
        int l = (sbk[e] >> 17) & 255;
        atomicAdd(&cnt[l], 1);
    }
    __syncthreads();
    int myc = cnt[tid];
    sA[tid] = myc;
    __syncthreads();
    for (int off = 1; off < 256; off <<= 1) {
        int r = sA[tid] + ((tid >= off) ? sA[tid - off] : 0);
        __syncthreads();
        sA[tid] = r;
        __syncthreads();
    }
    int gb = ebase + nodes0;
    lb[tid] = sA[tid] - myc;
    cur[tid] = 1;
    __syncthreads();
    if (tid < nnodes) {
        row_start[nodes0 + tid] = gb + lb[tid];
        csr[gb + lb[tid]] = nodes0 + tid;
    }
    __syncthreads();
    for (int e = tid; e < ecnt; e += 256) {
        int v = sbk[e];
        int l = (v >> 17) & 255;
        int src = v & 0x1FFFF;
        int r = atomicAdd(&cur[l], 1);
        csr[gb + lb[l] + r] = src;
    }
}

// h1[N,64](fp16) = x[N,128] @ W1[128,64] via MFMA 16x16x32 bf16 (R9).
__global__ __launch_bounds__(256) void k_gemm1(const float* __restrict__ x,
                                               const float* __restrict__ W1,
                                               const float* __restrict__ Wc,
                                               __half* __restrict__ h1, float* __restrict__ a_src,
                                               float* __restrict__ a_dst, int N) {
    __shared__ short wt[80 * 136];   // cols 0-63: W1^T; cols 64-79: Wc
    int tid = threadIdx.x;
    for (int i = tid; i < 128 * 64; i += 256) {
        int k = i >> 6, c = i & 63;
        wt[c * 136 + k] = f2bf(W1[i]);
    }
    for (int i = tid; i < 16 * 128; i += 256) {
        int col = i >> 7, k = i & 127;
        wt[(64 + col) * 136 + k] = f2bf(Wc[i]);
    }
    __syncthreads();
    int wave = tid >> 6, lane = tid & 63;
    int m = lane & 15, q = lane >> 4;
    int nbase = blockIdx.x * 64 + wave * 16;
    int anode = nbase + m;
    bool rowok = anode < N;
    const float* xrow = x + (size_t)(rowok ? anode : 0) * 128 + q * 8;

    float4v acc[5];
    #pragma unroll
    for (int ct = 0; ct < 5; ct++)
        #pragma unroll
        for (int r = 0; r < 4; r++) acc[ct][r] = 0.f;

    #pragma unroll
    for (int kc = 0; kc < 4; kc++) {
        float4 u0 = make_float4(0.f, 0.f, 0.f, 0.f), u1 = u0;
        if (rowok) {
            u0 = *(const float4*)(xrow + kc * 32);
            u1 = *(const float4*)(xrow + kc * 32 + 4);
        }
        short8 af;
        af[0] = f2bf(u0.x); af[1] = f2bf(u0.y); af[2] = f2bf(u0.z); af[3] = f2bf(u0.w);
        af[4] = f2bf(u1.x); af[5] = f2bf(u1.y); af[6] = f2bf(u1.z); af[7] = f2bf(u1.w);
        #pragma unroll
        for (int ct = 0; ct < 5; ct++) {
            short8 bf = *(const short8*)&wt[(ct * 16 + m) * 136 + kc * 32 + q * 8];
            acc[ct] = __builtin_amdgcn_mfma_f32_16x16x32_bf16(af, bf, acc[ct], 0, 0, 0);
        }
    }
    #pragma unroll
    for (int ct = 0; ct < 4; ct++) {
        #pragma unroll
        for (int r = 0; r < 4; r++) {
            int n = nbase + q * 4 + r;
            if (n < N) h1[(size_t)n * 64 + ct * 16 + m] = __float2half(acc[ct][r]);
        }
    }
    #pragma unroll
    for (int r = 0; r < 4; r++) {
        int n = nbase + q * 4 + r;
        if (n < N) {
            float v = acc[4][r];
            if (m < 4) a_src[n * 4 + m] = v;
            else if (m < 8) a_dst[n * 4 + (m - 4)] = v;
        }
    }
}

// layer-1 aggregation: 4 nodes per wave (16 lanes x 4 channels); out1 fp16
__global__ __launch_bounds__(256) void k_agg1(const int* __restrict__ row_start,
                                              const int* __restrict__ csr_src,
                                              const float* __restrict__ a_src,
                                              const float* __restrict__ a_dst,
                                              const __half* __restrict__ h1,
                                              const float* __restrict__ bias,
                                              __half* __restrict__ out1, int N) {
    __shared__ int   sidx[16][CAP1];
    __shared__ float sval[16][CAP1 * 4];
    int tid = threadIdx.x;
    int wave = tid >> 6, lane = tid & 63;
    int quad = lane >> 4, l16 = lane & 15;
    int slot = wave * 4 + quad;
    int node = blockIdx.x * 16 + slot;
    if (node >= N) return;
    int row = row_start[node];
    int deg = row_start[node + 1] - row;
    float4 ad = ((const float4*)a_dst)[node];
    float s0 = 0.f, s1 = 0.f, s2 = 0.f, s3 = 0.f;
    for (int j = l16; j < deg; j += 16) {
        int s = csr_src[row + j];
        float4 as = ((const float4*)a_src)[s];
        float e0 = __expf(LRELU(as.x + ad.x));
        float e1 = __expf(LRELU(as.y + ad.y));
        float e2 = __expf(LRELU(as.z + ad.z));
        float e3 = __expf(LRELU(as.w + ad.w));
        if (j < CAP1) {
            sidx[slot][j] = s;
            *(float4*)&sval[slot][j * 4] = make_float4(e0, e1, e2, e3);
        }
        s0 += e0; s1 += e1; s2 += e2; s3 += e3;
    }
    #pragma unroll
    for (int m = 1; m < 16; m <<= 1) {
        s0 += __shfl_xor(s0, m, 64);
        s1 += __shfl_xor(s1, m, 64);
        s2 += __shfl_xor(s2, m, 64);
        s3 += __shfl_xor(s3, m, 64);
    }
    int myh = l16 >> 2;
    float ssv = myh == 0 ? s0 : myh == 1 ? s1 : myh == 2 ? s2 : s3;
    float adm = myh == 0 ? ad.x : myh == 1 ? ad.y : myh == 2 ? ad.z : ad.w;
    float iv = 1.f / (ssv + 1e-16f);
    float A0 = 0.f, A1 = 0.f, A2 = 0.f, A3 = 0.f;
    float B0 = 0.f, B1 = 0.f, B2 = 0.f, B3 = 0.f;
    int dc = deg < CAP1 ? deg : CAP1;
    int j = 0;
    for (; j + 8 <= dc; j += 8) {
        int t[8]; float e[8]; float2 lo[8], hi[8];
        #pragma unroll
        for (int u = 0; u < 8; u++) {
            t[u] = sidx[slot][j + u];
            e[u] = sval[slot][(j + u) * 4 + myh];
        }
        #pragma unroll
        for (int u = 0; u < 8; u++) {
            union { float2 f; __half2 h[2]; } uu;
            uu.f = *(const float2*)&h1[(size_t)t[u] * 64 + l16 * 4];
            lo[u] = __half22float2(uu.h[0]);
            hi[u] = __half22float2(uu.h[1]);
        }
        #pragma unroll
        for (int u = 0; u < 8; u += 2) {
            A0 += e[u] * lo[u].x; A1 += e[u] * lo[u].y;
            A2 += e[u] * hi[u].x; A3 += e[u] * hi[u].y;
            B0 += e[u + 1] * lo[u + 1].x; B1 += e[u + 1] * lo[u + 1].y;
            B2 += e[u + 1] * hi[u + 1].x; B3 += e[u + 1] * hi[u + 1].y;
        }
    }
    for (; j < dc; j++) {
        int t = sidx[slot][j];
        float e = sval[slot][j * 4 + myh];
        union { float2 f; __half2 h[2]; } uu;
        uu.f = *(const float2*)&h1[(size_t)t * 64 + l16 * 4];
        float2 lo = __half22float2(uu.h[0]), hi = __half22float2(uu.h[1]);
        A0 += e * lo.x; A1 += e * lo.y; A2 += e * hi.x; A3 += e * hi.y;
    }
    for (; j < deg; j++) {   // deg > CAP1 fallback
        int s = csr_src[row + j];
        float e = __expf(LRELU(a_src[s * 4 + myh] + adm));
        union { float2 f; __half2 h[2]; } uu;
        uu.f = *(const float2*)&h1[(size_t)s * 64 + l16 * 4];
        float2 lo = __half22float2(uu.h[0]), hi = __half22float2(uu.h[1]);
        A0 += e * lo.x; A1 += e * lo.y; A2 += e * hi.x; A3 += e * hi.y;
    }
    A0 += B0; A1 += B1; A2 += B2; A3 += B3;
    float4 bb = ((const float4*)bias)[l16];
    float o0 = A0 * iv + bb.x;
    float o1 = A1 * iv + bb.y;
    float o2 = A2 * iv + bb.z;
    float o3 = A3 * iv + bb.w;
    o0 = (o0 > 0.f) ? o0 : (__expf(o0) - 1.f);
    o1 = (o1 > 0.f) ? o1 : (__expf(o1) - 1.f);
    o2 = (o2 > 0.f) ? o2 : (__expf(o2) - 1.f);
    o3 = (o3 > 0.f) ? o3 : (__expf(o3) - 1.f);
    union { __half2 h2v[2]; float2 f2; } pk;
    pk.h2v[0] = __floats2half2_rn(o0, o1);
    pk.h2v[1] = __floats2half2_rn(o2, o3);
    *(float2*)&out1[(size_t)node * 64 + l16 * 4] = pk.f2;
}

// h2[N,16](fp16) = out1[N,64](fp16) @ W2[64,16] via MFMA f16; att2 dots
// via folded Wc2/Wd2 columns (2nd B-frag) — shuffle-free epilogue.
__global__ __launch_bounds__(256) void k_gemm2(const __half* __restrict__ out1,
                                               const float* __restrict__ W2,
                                               const float* __restrict__ Wc2,
                                               __half* __restrict__ h2, float* __restrict__ a_src,
                                               float* __restrict__ a_dst, int N) {
    __shared__ _Float16 wt2[16][72];   // wt2[c][k] = W2[k][c]
    __shared__ _Float16 wtb[16][72];   // col0 = Wc2, col1 = Wd2, rest 0
    int tid = threadIdx.x;
    for (int i = tid; i < 16 * 64; i += 256) {
        int k = i >> 4, c = i & 15;
        wt2[c][k] = (_Float16)W2[i];
    }
    for (int i = tid; i < 16 * 64; i += 256) {
        int col = i >> 6, k = i & 63;
        wtb[col][k] = (col < 2) ? (_Float16)Wc2[col * 64 + k] : (_Float16)0.f;
    }
    __syncthreads();
    int wave = tid >> 6, lane = tid & 63;
    int m = lane & 15, q = lane >> 4;
    int nbase = blockIdx.x * 64 + wave * 16;
    int anode = nbase + m;
    bool ok = anode < N;
    const __half* arow = out1 + (size_t)(ok ? anode : 0) * 64 + q * 8;

    float4v c1 = {0.f, 0.f, 0.f, 0.f}, c2v = {0.f, 0.f, 0.f, 0.f};
    #pragma unroll
    for (int kc = 0; kc < 2; kc++) {
        half8 af = *(const half8*)(arow + kc * 32);
        half8 b1 = *(const half8*)&wt2[m][kc * 32 + q * 8];
        half8 b2 = *(const half8*)&wtb[m][kc * 32 + q * 8];
        c1  = __builtin_amdgcn_mfma_f32_16x16x32_f16(af, b1, c1, 0, 0, 0);
        c2v = __builtin_amdgcn_mfma_f32_16x16x32_f16(af, b2, c2v, 0, 0, 0);
    }
    #pragma unroll
    for (int r = 0; r < 4; r++) {
        int n = nbase + q * 4 + r;
        if (n < N) {
            h2[(size_t)n * 16 + m] = __float2half(c1[r]);
            if (m == 0) a_src[n] = c2v[r];
            else if (m == 1) a_dst[n] = c2v[r];
        }
    }
}

// layer-2 aggregation + bias + log_softmax; 4 nodes/wave, fp16 h2 gathers
__global__ __launch_bounds__(256) void k_agg2(const int* __restrict__ row_start,
                                              const int* __restrict__ csr_src,
                                              const float* __restrict__ a_src,
                                              const float* __restrict__ a_dst,
                                              const __half* __restrict__ h2,
                                              const float* __restrict__ bias,
                                              float* __restrict__ out, int N) {
    __shared__ int   sidx[16][CAP2];
    __shared__ float sval[16][CAP2];
    int tid = threadIdx.x;
    int wave = tid >> 6, lane = tid & 63;
    int quad = lane >> 4, l16 = lane & 15;
    int slot = wave * 4 + quad;
    int node = blockIdx.x * 16 + slot;
    if (node >= N) return;
    int row = row_start[node];
    int deg = row_start[node + 1] - row;
    float ad = a_dst[node];
    float sh = 0.f;
    for (int j = l16; j < deg; j += 16) {
        int s = csr_src[row + j];
        float e = __expf(LRELU(a_src[s] + ad));
        if (j < CAP2) { sidx[slot][j] = s; sval[slot][j] = e; }
        sh += e;
    }
    #pragma unroll
    for (int m = 1; m < 16; m <<= 1) sh += __shfl_xor(sh, m, 64);
    float iv = 1.f / (sh + 1e-16f);
    int cg = l16 & 7, eg = l16 >> 3;
    float ax = 0.f, ay = 0.f, bx = 0.f, by = 0.f;
    int dc = deg < CAP2 ? deg : CAP2;
    int j = eg;
    for (; j + 6 < dc; j += 8) {
        int t0 = sidx[slot][j], t1 = sidx[slot][j + 2];
        int t2 = sidx[slot][j + 4], t3 = sidx[slot][j + 6];
        float e0 = sval[slot][j], e1 = sval[slot][j + 2];
        float e2 = sval[slot][j + 4], e3 = sval[slot][j + 6];
        float2 g0 = __half22float2(*(const __half2*)&h2[(size_t)t0 * 16 + cg * 2]);
        float2 g1 = __half22float2(*(const __half2*)&h2[(size_t)t1 * 16 + cg * 2]);
        float2 g2 = __half22float2(*(const __half2*)&h2[(size_t)t2 * 16 + cg * 2]);
        float2 g3 = __half22float2(*(const __half2*)&h2[(size_t)t3 * 16 + cg * 2]);
        ax += e0 * g0.x + e2 * g2.x; ay += e0 * g0.y + e2 * g2.y;
        bx += e1 * g1.x + e3 * g3.x; by += e1 * g1.y + e3 * g3.y;
    }
    for (; j < deg; j += 2) {
        int s; float e;
        if (j < dc) { s = sidx[slot][j]; e = sval[slot][j]; }
        else { s = csr_src[row + j]; e = __expf(LRELU(a_src[s] + ad)); }
        float2 g = __half22float2(*(const __half2*)&h2[(size_t)s * 16 + cg * 2]);
        ax += e * g.x; ay += e * g.y;
    }
    ax += bx; ay += by;
    ax += __shfl_xor(ax, 8, 64);
    ay += __shfl_xor(ay, 8, 64);
    float2 bb = ((const float2*)bias)[cg];
    float vx = ax * iv + bb.x;
    float vy = ay * iv + bb.y;
    float mx = fmaxf(vx, vy);
    #pragma unroll
    for (int m = 1; m < 8; m <<= 1) mx = fmaxf(mx, __shfl_xor(mx, m, 64));
    float se = __expf(vx - mx) + __expf(vy - mx);
    #pragma unroll
    for (int m = 1; m < 8; m <<= 1) se += __shfl_xor(se, m, 64);
    float ls = mx + __logf(se);
    if (eg == 0)
        ((float2*)out)[(size_t)node * 8 + cg] = make_float2(vx - ls, vy - ls);
}

extern "C" void kernel_launch(void* const* d_in, const int* in_sizes, int n_in,
                              void* d_out, int out_size, void* d_ws, size_t ws_size,
                              hipStream_t stream) {
    const float* x        = (const float*)d_in[0];
    const int*   ei       = (const int*)d_in[1];
    const float* W1       = (const float*)d_in[2];
    const float* att_src1 = (const float*)d_in[3];
    const float* att_dst1 = (const float*)d_in[4];
    const float* bias1    = (const float*)d_in[5];
    const float* W2       = (const float*)d_in[6];
    const float* att_src2 = (const float*)d_in[7];
    const float* att_dst2 = (const float*)d_in[8];
    const float* bias2    = (const float*)d_in[9];
    float* out = (float*)d_out;

    const int N = in_sizes[0] / 128;
    const int E = in_sizes[1] / 2;
    const int NBK = (N + 255) >> BSH;

    char* p = (char*)d_ws;
    auto alloc = [&](size_t bytes) -> void* {
        void* r = (void*)p;
        p += (bytes + 255) & ~(size_t)255;
        return r;
    };
    __half* h1     = (__half*)alloc((size_t)N * 64 * 2);
    __half* out1   = (__half*)alloc((size_t)N * 64 * 2);
    __half* h2     = (__half*)alloc((size_t)N * 16 * 2);
    float* a_src1  = (float*)alloc((size_t)N * 4 * 4);
    float* a_dst1  = (float*)alloc((size_t)N * 4 * 4);
    float* a_src2  = (float*)alloc((size_t)N * 4);
    float* a_dst2  = (float*)alloc((size_t)N * 4);
    float* Wc      = (float*)alloc(16 * 128 * 4);
    float* Wc2     = (float*)alloc(2 * 64 * 4);
    int*   row_st  = (int*)alloc((size_t)(N + 1) * 4);
    int*   csr     = (int*)alloc((size_t)(E + N) * 4);
    int*   stage   = (int*)alloc((size_t)NBK * BCAP * 4);
    int*   cursor  = (int*)alloc((size_t)NBK * 4);
    (void)ws_size; (void)n_in; (void)out_size;

    hipMemsetAsync(cursor, 0, (size_t)NBK * 4, stream);
    k_scatter<<<(E + CHK - 1) / CHK, 256, 0, stream>>>(ei, cursor, stage, E, NBK);
    k_build<<<NBK, 256, 0, stream>>>(stage, cursor, row_st, csr,
                                     W1, att_src1, att_dst1, Wc,
                                     W2, att_src2, att_dst2, Wc2, NBK, E, N);
    k_gemm1<<<(N + 63) / 64, 256, 0, stream>>>(x, W1, Wc, h1, a_src1, a_dst1, N);
    k_agg1<<<(N + 15) / 16, 256, 0, stream>>>(row_st, csr, a_src1, a_dst1, h1, bias1, out1, N);
    k_gemm2<<<(N + 63) / 64, 256, 0, stream>>>(out1, W2, Wc2, h2, a_src2, a_dst2, N);
    k_agg2<<<(N + 15) / 16, 256, 0, stream>>>(row_st, csr, a_src2, a_dst2, h2, bias2, out, N);
}